// Round 2
// baseline (6433.765 us; speedup 1.0000x reference)
//
#include <hip/hip_runtime.h>
#include <math.h>

// ---------------------------------------------------------------------------
// OmniFluids2D forward on MI355X, fp32, all-GEMM formulation.
// B=4, NX=NY=256, W=64, L=4, modes=64, NF=5, ODIM=10.
//
// Spectral ops as GEMMs with precomputed trig tables:
//  y-fwd : Z[r=2m+c][i] = sum_y T_yf[r][y] * h[b,x,y,i]          (batch b,x)
//  x-fwd : Z[r=2k+c][i] = sum_x T_xf[r][x] * h[b,x,n,i]          (batch b,n)
//  mix   : L = Z * W (complex, contract channel i; IN-PLACE)      (batch b,mode)
//  y-inv : xy[y][o] = sum_r T_yi[y][r] * L[r][o]                  (batch b,x)
//  x-inv : xx[x][o] = sum_r T_xi[x][r] * L[r][o]  (+= into Rb)    (batch b,n)
// ---------------------------------------------------------------------------

__device__ __forceinline__ float gelu_f(float v) {
    return 0.5f * v * (1.0f + erff(v * 0.70710678118654752f));
}

// ------------------------- trig tables -------------------------------------
__global__ void k_tables(float* __restrict__ tab) {
    int idx = blockIdx.x * 256 + threadIdx.x;   // 0..131071
    int t = idx >> 15;
    int r = idx & 32767;
    const double PI = 3.14159265358979323846;
    const double s510 = 1.0 / sqrt(510.0);
    double v = 0.0;
    if (t == 0) {            // TAB_YF [row=2m+c][y]  (128x256)
        int row = r >> 8, y = r & 255;
        int m = row >> 1, c = row & 1;
        double ang = 2.0 * PI * (double)(m * y) / 256.0;
        v = (c == 0 ? cos(ang) : -sin(ang)) / 16.0;
    } else if (t == 1) {     // TAB_XF [row=2k+c][x]  (128x256)
        int row = r >> 8, xx = r & 255;
        int k = row >> 1, c = row & 1;
        if (c == 0) {
            v = 0.0;
            if (xx == 0)   v = s510;
            if (xx == 255) v = (k & 1) ? -s510 : s510;
        } else {
            double ang = PI * (double)(k * xx) / 255.0;
            v = -2.0 * s510 * sin(ang);
        }
    } else if (t == 2) {     // TAB_YI [y][row=2m+c]  (256x128)
        int y = r >> 7, row = r & 127;
        int m = row >> 1, c = row & 1;
        double ang = 2.0 * PI * (double)(m * y) / 256.0;
        if (c == 0) v = (m == 0 ? 1.0 : 2.0 * cos(ang)) / 16.0;
        else        v = (m == 0 ? 0.0 : -2.0 * sin(ang) / 16.0);
    } else {                 // TAB_XI [x][row=2k+c]  (256x128)
        int xx = r >> 7, row = r & 127;
        int k = row >> 1, c = row & 1;
        double ang = PI * (double)(k * xx) / 255.0;
        if (c == 0) v = s510 * (k == 0 ? 1.0 : 2.0 * cos(ang));
        else        v = (k == 0 ? 0.0 : -2.0 * s510 * sin(ang));
    }
    tab[idx] = (float)v;
}

// ------------------------- routing attention --------------------------------
__global__ void k_att(const float* __restrict__ params,
                      const float* __restrict__ w1, const float* __restrict__ b1,
                      const float* __restrict__ w2, const float* __restrict__ b2,
                      const float* __restrict__ w3, const float* __restrict__ b3,
                      float* __restrict__ att) {
    __shared__ float A1[128], A2[128], LG[4];
    int j = threadIdx.x;   // 128 threads
    for (int lay = 0; lay < 4; ++lay)
    for (int b = 0; b < 4; ++b) {
        float s = b1[lay * 128 + j];
        for (int p = 0; p < 8; ++p) s += params[b * 8 + p] * w1[(lay * 8 + p) * 128 + j];
        A1[j] = gelu_f(s);
        __syncthreads();
        s = b2[lay * 128 + j];
        for (int q = 0; q < 128; ++q) s += A1[q] * w2[(lay * 128 + q) * 128 + j];
        A2[j] = gelu_f(s);
        __syncthreads();
        if (j < 4) {
            float tacc = b3[lay * 4 + j];
            for (int q = 0; q < 128; ++q) tacc += A2[q] * w3[(lay * 128 + q) * 4 + j];
            LG[j] = tacc * 0.1f;
        }
        __syncthreads();
        if (j == 0) {
            float mx = fmaxf(fmaxf(LG[0], LG[1]), fmaxf(LG[2], LG[3]));
            float e0 = expf(LG[0] - mx), e1 = expf(LG[1] - mx);
            float e2 = expf(LG[2] - mx), e3 = expf(LG[3] - mx);
            float inv = 1.0f / (e0 + e1 + e2 + e3);
            att[lay * 16 + b * 4 + 0] = e0 * inv;
            att[lay * 16 + b * 4 + 1] = e1 * inv;
            att[lay * 16 + b * 4 + 2] = e2 * inv;
            att[lay * 16 + b * 4 + 3] = e3 * inv;
        }
        __syncthreads();
    }
}

// ------------------------- input embedding ----------------------------------
__global__ __launch_bounds__(256) void k_embed(const float* __restrict__ xin,
                        const float* __restrict__ inw,
                        const float* __restrict__ inb, float* __restrict__ H) {
    long gid = (long)blockIdx.x * 256 + threadIdx.x;
    long px = gid >> 6;
    int ch = (int)(gid & 63);
    int y = (int)(px & 255), xi = (int)((px >> 8) & 255);
    const float* xp = xin + px * 5;
    float v[7];
    v[0] = xp[0]; v[1] = xp[1]; v[2] = xp[2]; v[3] = xp[3]; v[4] = xp[4];
    const float STEP = 6.283185307179586f / 256.0f;
    v[5] = xi * STEP;
    v[6] = y * STEP;
    float s = inb[ch];
    #pragma unroll
    for (int p = 0; p < 7; ++p) s += v[p] * inw[p * 64 + ch];
    H[gid] = gelu_f(s);
}

// ------------------------- per-layer W generation ---------------------------
// out: WR/WI [b][m][i*64+o] at b*262144 + i*64 + m*4096 + o,
// from fw[k][i][o][m][c] per-layer slab (i stride 8192, k stride 524288).
__global__ __launch_bounds__(256) void k_wgen(const float* __restrict__ fw,
                       const float* __restrict__ att,   // + lay*16
                       float* __restrict__ WRo, float* __restrict__ WIo) {
    int ii = blockIdx.x;   // 64 (channel i)
    int b  = blockIdx.y;   // 4
    int tid = threadIdx.x;
    float av[4];
    av[0] = att[b * 4 + 0]; av[1] = att[b * 4 + 1];
    av[2] = att[b * 4 + 2]; av[3] = att[b * 4 + 3];
    float acc[32];
    #pragma unroll
    for (int j = 0; j < 32; ++j) acc[j] = 0.0f;
    const float* base = fw + (long)ii * 8192;
    for (int k = 0; k < 4; ++k) {
        const float* p = base + (long)k * 524288;
        float a = av[k];
        #pragma unroll
        for (int j = 0; j < 32; ++j) acc[j] += a * p[tid + j * 256];
    }
    __shared__ float ldsR[64 * 65], ldsI[64 * 65];
    #pragma unroll
    for (int j = 0; j < 32; ++j) {
        int l = tid + j * 256;                 // l over [o][m][c]
        int o = l >> 7, m = (l >> 1) & 63, c = l & 1;
        (c ? ldsI : ldsR)[o * 65 + m] = acc[j];
    }
    __syncthreads();
    long ob = (long)b * 262144 + (long)ii * 64;
    for (int w = tid; w < 4096; w += 256) {
        int m = w >> 6, o = w & 63;
        WRo[ob + (long)m * 4096 + o] = ldsR[o * 65 + m];
        WIo[ob + (long)m * 4096 + o] = ldsI[o * 65 + m];
    }
}

// ------------------------- generic 64x64-tile GEMM --------------------------
// C[m][n] = sum_k A[m][k] * B[k][n]  (+bias/relu/accum), batched.
// A: shared across batch, row-major, stride aRow.
// batch g -> gh=g>>gShift, gl=g&mask; base offsets via (hi,lo).
// B row addr: (k>>1)*bSK + (k&1)*bSC ; C row addr: (m>>1)*cSK + (m&1)*cSC.
__global__ __launch_bounds__(256) void gemm64(
    const float* __restrict__ A, int aRow,
    const float* __restrict__ B, long bHi, long bLo, int bSK, int bSC,
    float* __restrict__ C, long cHi, long cLo, int cSK, int cSC,
    int gShift, int K, const float* __restrict__ bias, int flags)
{
    __shared__ float As[64][68];
    __shared__ float Bs[64][64];
    int nt = blockIdx.x, mt = blockIdx.y, g = blockIdx.z;
    int gh = g >> gShift, gl = g & ((1 << gShift) - 1);
    long bBase = (long)gh * bHi + (long)gl * bLo;
    long cBase = (long)gh * cHi + (long)gl * cLo;
    int m0 = mt * 64, n0 = nt * 64;
    int tid = threadIdx.x, ty = tid >> 4, tx = tid & 15;
    float acc[4][4] = {{0.f,0.f,0.f,0.f},{0.f,0.f,0.f,0.f},{0.f,0.f,0.f,0.f},{0.f,0.f,0.f,0.f}};
    for (int kc = 0; kc < K; kc += 64) {
        #pragma unroll
        for (int j = 0; j < 16; ++j) {
            int l = tid + j * 256;
            int mm = l >> 6, kk = l & 63;
            As[mm][kk] = A[(long)(m0 + mm) * aRow + kc + kk];
        }
        #pragma unroll
        for (int j = 0; j < 16; ++j) {
            int l = tid + j * 256;
            int kk = l >> 6, nn = l & 63;
            int k = kc + kk;
            Bs[kk][nn] = B[bBase + (long)(k >> 1) * bSK + (long)(k & 1) * bSC + n0 + nn];
        }
        __syncthreads();
        #pragma unroll
        for (int s4 = 0; s4 < 64; s4 += 4) {
            float ar[4][4];
            #pragma unroll
            for (int rr = 0; rr < 4; ++rr)
                *(float4*)&ar[rr][0] = *(const float4*)&As[ty * 4 + rr][s4];
            #pragma unroll
            for (int ss = 0; ss < 4; ++ss) {
                float4 b4 = *(const float4*)&Bs[s4 + ss][tx * 4];
                #pragma unroll
                for (int rr = 0; rr < 4; ++rr) {
                    float a = ar[rr][ss];
                    acc[rr][0] += a * b4.x; acc[rr][1] += a * b4.y;
                    acc[rr][2] += a * b4.z; acc[rr][3] += a * b4.w;
                }
            }
        }
        __syncthreads();
    }
    #pragma unroll
    for (int rr = 0; rr < 4; ++rr) {
        int m = m0 + ty * 4 + rr;
        long addr = cBase + (long)(m >> 1) * cSK + (long)(m & 1) * cSC + n0 + tx * 4;
        #pragma unroll
        for (int cc = 0; cc < 4; ++cc) {
            float v = acc[rr][cc];
            if (bias) v += bias[n0 + tx * 4 + cc];
            if (flags & 1) v = fmaxf(v, 0.0f);
            if (flags & 2) v += C[addr + cc];
            C[addr + cc] = v;
        }
    }
}

// ------------------------- complex mode-mix (IN-PLACE capable) --------------
// L[row][o](complex) = sum_i Z[row][i](complex) * W[i][o](complex)
// batch g=(b,mode); Z/L layout: base(b,mode) + row*zRow + {0|64} + idx
// Safe in-place: each block stages its own slab in LDS before overwriting.
__global__ __launch_bounds__(256) void k_mix(
    const float* Z, const float* __restrict__ WR, const float* __restrict__ WI,
    float* L, long zHi, long zM, int zRow)
{
    int rt = blockIdx.x, g = blockIdx.y;
    int b = g >> 6, mk = g & 63;
    long base = (long)b * zHi + (long)mk * zM;
    long wb = (long)b * 262144 + (long)mk * 4096;
    __shared__ float WRs[64][64], WIs[64][64];
    __shared__ float ZRs[64][33], ZIs[64][33];
    int tid = threadIdx.x, ty = tid >> 4, tx = tid & 15;
    #pragma unroll
    for (int j = 0; j < 16; ++j) {
        int l = tid + j * 256;
        WRs[l >> 6][l & 63] = WR[wb + l];
        WIs[l >> 6][l & 63] = WI[wb + l];
    }
    int r0 = rt * 64;
    float aR[4][4] = {{0.f,0.f,0.f,0.f},{0.f,0.f,0.f,0.f},{0.f,0.f,0.f,0.f},{0.f,0.f,0.f,0.f}};
    float aI[4][4] = {{0.f,0.f,0.f,0.f},{0.f,0.f,0.f,0.f},{0.f,0.f,0.f,0.f},{0.f,0.f,0.f,0.f}};
    for (int ch = 0; ch < 2; ++ch) {
        __syncthreads();
        #pragma unroll
        for (int j = 0; j < 8; ++j) {
            int l = tid + j * 256;
            int row = l >> 5, i = l & 31;
            long a = base + (long)(r0 + row) * zRow + ch * 32 + i;
            ZRs[row][i] = Z[a];
            ZIs[row][i] = Z[a + 64];
        }
        __syncthreads();
        #pragma unroll
        for (int i2 = 0; i2 < 32; ++i2) {
            int i = ch * 32 + i2;
            float zr[4], zi[4];
            #pragma unroll
            for (int rr = 0; rr < 4; ++rr) {
                zr[rr] = ZRs[ty * 4 + rr][i2];
                zi[rr] = ZIs[ty * 4 + rr][i2];
            }
            float4 wr = *(const float4*)&WRs[i][tx * 4];
            float4 wi = *(const float4*)&WIs[i][tx * 4];
            #pragma unroll
            for (int rr = 0; rr < 4; ++rr) {
                aR[rr][0] += zr[rr] * wr.x - zi[rr] * wi.x;
                aI[rr][0] += zr[rr] * wi.x + zi[rr] * wr.x;
                aR[rr][1] += zr[rr] * wr.y - zi[rr] * wi.y;
                aI[rr][1] += zr[rr] * wi.y + zi[rr] * wr.y;
                aR[rr][2] += zr[rr] * wr.z - zi[rr] * wi.z;
                aI[rr][2] += zr[rr] * wi.z + zi[rr] * wr.z;
                aR[rr][3] += zr[rr] * wr.w - zi[rr] * wi.w;
                aI[rr][3] += zr[rr] * wi.w + zi[rr] * wr.w;
            }
        }
    }
    #pragma unroll
    for (int rr = 0; rr < 4; ++rr) {
        long a = base + (long)(r0 + ty * 4 + rr) * zRow + tx * 4;
        #pragma unroll
        for (int cc = 0; cc < 4; ++cc) {
            L[a + cc] = aR[rr][cc];
            L[a + 64 + cc] = aI[rr][cc];
        }
    }
}

// ------------------------- FF second GEMM + LayerNorm -----------------------
// t = T1(rows,256) @ W1(256,64) + b1 ; LN(t) ; H += ln  (or H = gelu(ln) last)
__global__ __launch_bounds__(256) void k_ff2(
    const float* __restrict__ T1, const float* __restrict__ W1,
    const float* __restrict__ b1, const float* __restrict__ g1,
    const float* __restrict__ be1, float* __restrict__ H, int last)
{
    __shared__ float As[64][68];
    __shared__ float Bs[64][64];
    int mt = blockIdx.x;
    int tid = threadIdx.x, ty = tid >> 4, tx = tid & 15;
    int m0 = mt * 64;
    float acc[4][4] = {{0.f,0.f,0.f,0.f},{0.f,0.f,0.f,0.f},{0.f,0.f,0.f,0.f},{0.f,0.f,0.f,0.f}};
    for (int kc = 0; kc < 256; kc += 64) {
        #pragma unroll
        for (int j = 0; j < 16; ++j) {
            int l = tid + j * 256;
            int mm = l >> 6, kk = l & 63;
            As[mm][kk] = T1[(long)(m0 + mm) * 256 + kc + kk];
        }
        #pragma unroll
        for (int j = 0; j < 16; ++j) {
            int l = tid + j * 256;
            int kk = l >> 6, nn = l & 63;
            Bs[kk][nn] = W1[(long)(kc + kk) * 64 + nn];
        }
        __syncthreads();
        #pragma unroll
        for (int s4 = 0; s4 < 64; s4 += 4) {
            float ar[4][4];
            #pragma unroll
            for (int rr = 0; rr < 4; ++rr)
                *(float4*)&ar[rr][0] = *(const float4*)&As[ty * 4 + rr][s4];
            #pragma unroll
            for (int ss = 0; ss < 4; ++ss) {
                float4 b4 = *(const float4*)&Bs[s4 + ss][tx * 4];
                #pragma unroll
                for (int rr = 0; rr < 4; ++rr) {
                    float a = ar[rr][ss];
                    acc[rr][0] += a * b4.x; acc[rr][1] += a * b4.y;
                    acc[rr][2] += a * b4.z; acc[rr][3] += a * b4.w;
                }
            }
        }
        __syncthreads();
    }
    float bia[4], gg[4], bb[4];
    #pragma unroll
    for (int cc = 0; cc < 4; ++cc) {
        bia[cc] = b1[tx * 4 + cc];
        gg[cc]  = g1[tx * 4 + cc];
        bb[cc]  = be1[tx * 4 + cc];
    }
    #pragma unroll
    for (int rr = 0; rr < 4; ++rr) {
        float t0 = acc[rr][0] + bia[0], t1 = acc[rr][1] + bia[1];
        float t2 = acc[rr][2] + bia[2], t3 = acc[rr][3] + bia[3];
        float s = t0 + t1 + t2 + t3;
        float q = t0 * t0 + t1 * t1 + t2 * t2 + t3 * t3;
        for (int d = 1; d < 16; d <<= 1) {
            s += __shfl_xor(s, d, 64);
            q += __shfl_xor(q, d, 64);
        }
        float mean = s * (1.0f / 64.0f);
        float var = q * (1.0f / 64.0f) - mean * mean;
        float inv = rsqrtf(var + 1e-5f);
        long addr = (long)(m0 + ty * 4 + rr) * 64 + tx * 4;
        float tv[4] = {t0, t1, t2, t3};
        #pragma unroll
        for (int cc = 0; cc < 4; ++cc) {
            float v = (tv[cc] - mean) * inv * gg[cc] + bb[cc];
            if (last) H[addr + cc] = gelu_f(v);
            else      H[addr + cc] += v;
        }
    }
}

// ------------------------- output heads -------------------------------------
__global__ __launch_bounds__(64) void k_head(
    const float* __restrict__ H, const float* __restrict__ x0,
    const float* __restrict__ fa_w, const float* __restrict__ fa_b,
    const float* __restrict__ fb_w, const float* __restrict__ fb_b,
    const float* __restrict__ c1w, const float* __restrict__ c1b,
    const float* __restrict__ c2w, const float* __restrict__ c2b,
    float* __restrict__ out)
{
    int f = blockIdx.y;
    long px0 = (long)blockIdx.x * 64;
    int tid = threadIdx.x;
    __shared__ float Ws[64][70];
    __shared__ float bs[70];
    __shared__ float w1s[8][12], b1s[8], w2s[8][12];
    __shared__ float Hs[64][65];
    __shared__ float ha[64][71];
    for (int l = tid; l < 64 * 36; l += 64) Ws[l / 36][l % 36] = fa_w[(long)f * 2304 + l];
    for (int l = tid; l < 64 * 34; l += 64) Ws[l / 34][36 + l % 34] = fb_w[(long)f * 2176 + l];
    if (tid < 36) bs[tid] = fa_b[f * 36 + tid];
    if (tid < 34) bs[36 + tid] = fb_b[f * 34 + tid];
    for (int l = tid; l < 96; l += 64) {
        w1s[l / 12][l % 12] = c1w[f * 96 + l];
        w2s[l / 12][l % 12] = c2w[f * 96 + l];
    }
    if (tid < 8) b1s[tid] = c1b[f * 8 + tid];
    for (int it = 0; it < 64; ++it) Hs[it][tid] = H[(px0 + it) * 64 + tid];
    __syncthreads();
    float hreg[64];
    #pragma unroll
    for (int k = 0; k < 64; ++k) hreg[k] = Hs[tid][k];
    for (int j = 0; j < 70; ++j) {
        float s = bs[j];
        #pragma unroll
        for (int k = 0; k < 64; ++k) s += hreg[k] * Ws[k][j];
        ha[tid][j] = gelu_f(s);
    }
    float b2v = c2b[f];
    float u2[10];
    #pragma unroll
    for (int d = 0; d < 10; ++d) u2[d] = b2v;
    for (int c = 0; c < 8; ++c) {
        float u1[30];
        #pragma unroll
        for (int p = 0; p < 30; ++p) {
            float s = b1s[c];
            #pragma unroll
            for (int t = 0; t < 12; ++t) s += ha[tid][2 * p + t] * w1s[c][t];
            u1[p] = gelu_f(s);
        }
        #pragma unroll
        for (int p2 = 0; p2 < 10; ++p2) {
            #pragma unroll
            for (int t = 0; t < 12; ++t) u2[p2] += u1[2 * p2 + t] * w2s[c][t];
        }
    }
    long px = px0 + tid;
    float xv = x0[px * 5 + f];
    #pragma unroll
    for (int d = 0; d < 10; ++d)
        out[px * 50 + f * 10 + d] = xv + u2[d] * (float)(d + 1) * 0.1f;
}

// ---------------------------------------------------------------------------
extern "C" void kernel_launch(void* const* d_in, const int* in_sizes, int n_in,
                              void* d_out, int out_size, void* d_ws, size_t ws_size,
                              hipStream_t stream) {
    (void)in_sizes; (void)n_in; (void)out_size; (void)ws_size;
    const float* xin    = (const float*)d_in[0];
    const float* params = (const float*)d_in[1];
    const float* in_w   = (const float*)d_in[2];
    const float* in_b   = (const float*)d_in[3];
    const float* fnu_w1 = (const float*)d_in[4];
    const float* fnu_b1 = (const float*)d_in[5];
    const float* fnu_w2 = (const float*)d_in[6];
    const float* fnu_b2 = (const float*)d_in[7];
    const float* fnu_w3 = (const float*)d_in[8];
    const float* fnu_b3 = (const float*)d_in[9];
    const float* fw_y   = (const float*)d_in[10];
    const float* fw_x   = (const float*)d_in[11];
    const float* ff_w0  = (const float*)d_in[12];
    const float* ff_b0  = (const float*)d_in[13];
    const float* ff_w1  = (const float*)d_in[14];
    const float* ff_b1  = (const float*)d_in[15];
    const float* ln_g   = (const float*)d_in[16];
    const float* ln_b   = (const float*)d_in[17];
    const float* fa_w   = (const float*)d_in[18];
    const float* fa_b   = (const float*)d_in[19];
    const float* fb_w   = (const float*)d_in[20];
    const float* fb_b   = (const float*)d_in[21];
    const float* c1_w   = (const float*)d_in[22];
    const float* c1_b   = (const float*)d_in[23];
    const float* c2_w   = (const float*)d_in[24];
    const float* c2_b   = (const float*)d_in[25];
    float* out = (float*)d_out;
    float* ws  = (float*)d_ws;

    // workspace layout (floats); total 44,171,328 (~177 MB)
    float* tab   = ws;                 // 131072
    float* tabYF = ws + 0;
    float* tabXF = ws + 32768;
    float* tabYI = ws + 65536;
    float* tabXI = ws + 98304;
    float* att   = ws + 131072;        // 64
    float* H     = ws + 131136;        // 16777216  [b][x][y][ch]
    float* WRb   = ws + 16908352;      // 1048576
    float* WIb   = ws + 17956928;      // 1048576
    float* Zb    = ws + 19005504;      // 8388608  (Z, L in-place, T1 reuse)
    float* Rb    = ws + 27394112;      // 16777216 [b][x][y][ch]
    float* T1    = Zb;                 // 4194304 needed per FF chunk

    k_tables<<<512, 256, 0, stream>>>(tab);
    k_att<<<1, 128, 0, stream>>>(params, fnu_w1, fnu_b1, fnu_w2, fnu_b2, fnu_w3, fnu_b3, att);
    k_embed<<<65536, 256, 0, stream>>>(xin, in_w, in_b, H);

    for (int lay = 0; lay < 4; ++lay) {
        const float* attL = att + lay * 16;
        // -------- Y branch (periodic rfft) --------
        k_wgen<<<dim3(64, 4), 256, 0, stream>>>(fw_y + (long)lay * 2097152, attL, WRb, WIb);
        gemm64<<<dim3(1, 2, 1024), 256, 0, stream>>>(
            tabYF, 256,
            H, 4194304L, 16384L, 128, 64,
            Zb, 2097152L, 8192L, 128, 64,
            8, 256, nullptr, 0);
        k_mix<<<dim3(4, 256), 256, 0, stream>>>(Zb, WRb, WIb, Zb, 2097152L, 128L, 8192);
        gemm64<<<dim3(1, 4, 1024), 256, 0, stream>>>(
            tabYI, 128,
            Zb, 2097152L, 8192L, 128, 64,
            Rb, 4194304L, 16384L, 128, 64,
            8, 128, nullptr, 0);
        // -------- X branch (Dirichlet DST) --------
        k_wgen<<<dim3(64, 4), 256, 0, stream>>>(fw_x + (long)lay * 2097152, attL, WRb, WIb);
        gemm64<<<dim3(1, 2, 1024), 256, 0, stream>>>(
            tabXF, 256,
            H, 4194304L, 64L, 32768, 16384,
            Zb, 2097152L, 128L, 32768, 64,
            8, 256, nullptr, 0);
        k_mix<<<dim3(4, 256), 256, 0, stream>>>(Zb, WRb, WIb, Zb, 2097152L, 32768L, 128);
        gemm64<<<dim3(1, 4, 1024), 256, 0, stream>>>(
            tabXI, 128,
            Zb, 2097152L, 128L, 32768, 64,
            Rb, 4194304L, 64L, 32768, 16384,
            8, 128, nullptr, 2);           // accumulate xx into xy
        // -------- FeedForward + LN (+residual / final gelu) --------
        for (int q = 0; q < 16; ++q) {
            gemm64<<<dim3(4, 256, 1), 256, 0, stream>>>(
                Rb + (long)q * 1048576, 64,
                ff_w0 + (long)lay * 16384, 0L, 0L, 512, 256,
                T1, 0L, 0L, 512, 256,
                0, 64, ff_b0 + lay * 256, 1);   // relu
            k_ff2<<<256, 256, 0, stream>>>(
                T1, ff_w1 + (long)lay * 16384, ff_b1 + lay * 64,
                ln_g + lay * 64, ln_b + lay * 64,
                H + (long)q * 1048576, (lay == 3) ? 1 : 0);
        }
    }
    k_head<<<dim3(4096, 5), 64, 0, stream>>>(H, xin, fa_w, fa_b, fb_w, fb_b,
                                             c1_w, c1_b, c2_w, c2_b, out);
}

// Round 3
// 4567.719 us; speedup vs baseline: 1.4085x; 1.4085x over previous
//
#include <hip/hip_runtime.h>
#include <math.h>

// ---------------------------------------------------------------------------
// OmniFluids2D forward on MI355X, fp32, all-GEMM formulation.
// B=4, NX=NY=256, W=64, L=4, modes=64, NF=5, ODIM=10.
// ---------------------------------------------------------------------------

__device__ __forceinline__ float gelu_f(float v) {
    return 0.5f * v * (1.0f + erff(v * 0.70710678118654752f));
}

// ------------------------- trig tables -------------------------------------
__global__ void k_tables(float* __restrict__ tab) {
    int idx = blockIdx.x * 256 + threadIdx.x;   // 0..131071
    int t = idx >> 15;
    int r = idx & 32767;
    const double PI = 3.14159265358979323846;
    const double s510 = 1.0 / sqrt(510.0);
    double v = 0.0;
    if (t == 0) {            // TAB_YF [row=2m+c][y]  (128x256)
        int row = r >> 8, y = r & 255;
        int m = row >> 1, c = row & 1;
        double ang = 2.0 * PI * (double)(m * y) / 256.0;
        v = (c == 0 ? cos(ang) : -sin(ang)) / 16.0;
    } else if (t == 1) {     // TAB_XF [row=2k+c][x]  (128x256)
        int row = r >> 8, xx = r & 255;
        int k = row >> 1, c = row & 1;
        if (c == 0) {
            v = 0.0;
            if (xx == 0)   v = s510;
            if (xx == 255) v = (k & 1) ? -s510 : s510;
        } else {
            double ang = PI * (double)(k * xx) / 255.0;
            v = -2.0 * s510 * sin(ang);
        }
    } else if (t == 2) {     // TAB_YI [y][row=2m+c]  (256x128)
        int y = r >> 7, row = r & 127;
        int m = row >> 1, c = row & 1;
        double ang = 2.0 * PI * (double)(m * y) / 256.0;
        if (c == 0) v = (m == 0 ? 1.0 : 2.0 * cos(ang)) / 16.0;
        else        v = (m == 0 ? 0.0 : -2.0 * sin(ang) / 16.0);
    } else {                 // TAB_XI [x][row=2k+c]  (256x128)
        int xx = r >> 7, row = r & 127;
        int k = row >> 1, c = row & 1;
        double ang = PI * (double)(k * xx) / 255.0;
        if (c == 0) v = s510 * (k == 0 ? 1.0 : 2.0 * cos(ang));
        else        v = (k == 0 ? 0.0 : -2.0 * s510 * sin(ang));
    }
    tab[idx] = (float)v;
}

// ------------------------- routing attention --------------------------------
__global__ void k_att(const float* __restrict__ params,
                      const float* __restrict__ w1, const float* __restrict__ b1,
                      const float* __restrict__ w2, const float* __restrict__ b2,
                      const float* __restrict__ w3, const float* __restrict__ b3,
                      float* __restrict__ att) {
    __shared__ float A1[128], A2[128], LG[4];
    int j = threadIdx.x;   // 128 threads
    for (int lay = 0; lay < 4; ++lay)
    for (int b = 0; b < 4; ++b) {
        float s = b1[lay * 128 + j];
        for (int p = 0; p < 8; ++p) s += params[b * 8 + p] * w1[(lay * 8 + p) * 128 + j];
        A1[j] = gelu_f(s);
        __syncthreads();
        s = b2[lay * 128 + j];
        for (int q = 0; q < 128; ++q) s += A1[q] * w2[(lay * 128 + q) * 128 + j];
        A2[j] = gelu_f(s);
        __syncthreads();
        if (j < 4) {
            float tacc = b3[lay * 4 + j];
            for (int q = 0; q < 128; ++q) tacc += A2[q] * w3[(lay * 128 + q) * 4 + j];
            LG[j] = tacc * 0.1f;
        }
        __syncthreads();
        if (j == 0) {
            float mx = fmaxf(fmaxf(LG[0], LG[1]), fmaxf(LG[2], LG[3]));
            float e0 = expf(LG[0] - mx), e1 = expf(LG[1] - mx);
            float e2 = expf(LG[2] - mx), e3 = expf(LG[3] - mx);
            float inv = 1.0f / (e0 + e1 + e2 + e3);
            att[lay * 16 + b * 4 + 0] = e0 * inv;
            att[lay * 16 + b * 4 + 1] = e1 * inv;
            att[lay * 16 + b * 4 + 2] = e2 * inv;
            att[lay * 16 + b * 4 + 3] = e3 * inv;
        }
        __syncthreads();
    }
}

// ------------------------- input embedding ----------------------------------
__global__ __launch_bounds__(256) void k_embed(const float* __restrict__ xin,
                        const float* __restrict__ inw,
                        const float* __restrict__ inb, float* __restrict__ H) {
    long gid = (long)blockIdx.x * 256 + threadIdx.x;
    long px = gid >> 6;
    int ch = (int)(gid & 63);
    int y = (int)(px & 255), xi = (int)((px >> 8) & 255);
    const float* xp = xin + px * 5;
    float v[7];
    v[0] = xp[0]; v[1] = xp[1]; v[2] = xp[2]; v[3] = xp[3]; v[4] = xp[4];
    const float STEP = 6.283185307179586f / 256.0f;
    v[5] = xi * STEP;
    v[6] = y * STEP;
    float s = inb[ch];
    #pragma unroll
    for (int p = 0; p < 7; ++p) s += v[p] * inw[p * 64 + ch];
    H[gid] = gelu_f(s);
}

// ------------------------- per-layer W generation ---------------------------
__global__ __launch_bounds__(256) void k_wgen(const float* __restrict__ fw,
                       const float* __restrict__ att,   // + lay*16
                       float* __restrict__ WRo, float* __restrict__ WIo) {
    int ii = blockIdx.x;   // 64 (channel i)
    int b  = blockIdx.y;   // 4
    int tid = threadIdx.x;
    float av[4];
    av[0] = att[b * 4 + 0]; av[1] = att[b * 4 + 1];
    av[2] = att[b * 4 + 2]; av[3] = att[b * 4 + 3];
    float acc[32];
    #pragma unroll
    for (int j = 0; j < 32; ++j) acc[j] = 0.0f;
    const float* base = fw + (long)ii * 8192;
    for (int k = 0; k < 4; ++k) {
        const float* p = base + (long)k * 524288;
        float a = av[k];
        #pragma unroll
        for (int j = 0; j < 32; ++j) acc[j] += a * p[tid + j * 256];
    }
    __shared__ float ldsR[64 * 65], ldsI[64 * 65];
    #pragma unroll
    for (int j = 0; j < 32; ++j) {
        int l = tid + j * 256;                 // l over [o][m][c]
        int o = l >> 7, m = (l >> 1) & 63, c = l & 1;
        (c ? ldsI : ldsR)[o * 65 + m] = acc[j];
    }
    __syncthreads();
    long ob = (long)b * 262144 + (long)ii * 64;
    for (int w = tid; w < 4096; w += 256) {
        int m = w >> 6, o = w & 63;
        WRo[ob + (long)m * 4096 + o] = ldsR[o * 65 + m];
        WIo[ob + (long)m * 4096 + o] = ldsI[o * 65 + m];
    }
}

// ------------------------- generic 64x64-tile GEMM --------------------------
__global__ __launch_bounds__(256) void gemm64(
    const float* __restrict__ A, int aRow,
    const float* __restrict__ B, long bHi, long bLo, int bSK, int bSC,
    float* __restrict__ C, long cHi, long cLo, int cSK, int cSC,
    int gShift, int K, const float* __restrict__ bias, int flags)
{
    __shared__ float As[64][68];
    __shared__ float Bs[64][64];
    int nt = blockIdx.x, mt = blockIdx.y, g = blockIdx.z;
    int gh = g >> gShift, gl = g & ((1 << gShift) - 1);
    long bBase = (long)gh * bHi + (long)gl * bLo;
    long cBase = (long)gh * cHi + (long)gl * cLo;
    int m0 = mt * 64, n0 = nt * 64;
    int tid = threadIdx.x, ty = tid >> 4, tx = tid & 15;
    float acc[4][4] = {{0.f,0.f,0.f,0.f},{0.f,0.f,0.f,0.f},{0.f,0.f,0.f,0.f},{0.f,0.f,0.f,0.f}};
    for (int kc = 0; kc < K; kc += 64) {
        #pragma unroll
        for (int j = 0; j < 16; ++j) {
            int l = tid + j * 256;
            int mm = l >> 6, kk = l & 63;
            As[mm][kk] = A[(long)(m0 + mm) * aRow + kc + kk];
        }
        #pragma unroll
        for (int j = 0; j < 16; ++j) {
            int l = tid + j * 256;
            int kk = l >> 6, nn = l & 63;
            int k = kc + kk;
            Bs[kk][nn] = B[bBase + (long)(k >> 1) * bSK + (long)(k & 1) * bSC + n0 + nn];
        }
        __syncthreads();
        #pragma unroll
        for (int s4 = 0; s4 < 64; s4 += 4) {
            float ar[4][4];
            #pragma unroll
            for (int rr = 0; rr < 4; ++rr)
                *(float4*)&ar[rr][0] = *(const float4*)&As[ty * 4 + rr][s4];
            #pragma unroll
            for (int ss = 0; ss < 4; ++ss) {
                float4 b4 = *(const float4*)&Bs[s4 + ss][tx * 4];
                #pragma unroll
                for (int rr = 0; rr < 4; ++rr) {
                    float a = ar[rr][ss];
                    acc[rr][0] += a * b4.x; acc[rr][1] += a * b4.y;
                    acc[rr][2] += a * b4.z; acc[rr][3] += a * b4.w;
                }
            }
        }
        __syncthreads();
    }
    #pragma unroll
    for (int rr = 0; rr < 4; ++rr) {
        int m = m0 + ty * 4 + rr;
        long addr = cBase + (long)(m >> 1) * cSK + (long)(m & 1) * cSC + n0 + tx * 4;
        #pragma unroll
        for (int cc = 0; cc < 4; ++cc) {
            float v = acc[rr][cc];
            if (bias) v += bias[n0 + tx * 4 + cc];
            if (flags & 1) v = fmaxf(v, 0.0f);
            if (flags & 2) v += C[addr + cc];
            C[addr + cc] = v;
        }
    }
}

// ------------------------- complex mode-mix (IN-PLACE capable) --------------
__global__ __launch_bounds__(256) void k_mix(
    const float* Z, const float* __restrict__ WR, const float* __restrict__ WI,
    float* L, long zHi, long zM, int zRow)
{
    int rt = blockIdx.x, g = blockIdx.y;
    int b = g >> 6, mk = g & 63;
    long base = (long)b * zHi + (long)mk * zM;
    long wb = (long)b * 262144 + (long)mk * 4096;
    __shared__ float WRs[64][64], WIs[64][64];
    __shared__ float ZRs[64][33], ZIs[64][33];
    int tid = threadIdx.x, ty = tid >> 4, tx = tid & 15;
    #pragma unroll
    for (int j = 0; j < 16; ++j) {
        int l = tid + j * 256;
        WRs[l >> 6][l & 63] = WR[wb + l];
        WIs[l >> 6][l & 63] = WI[wb + l];
    }
    int r0 = rt * 64;
    float aR[4][4] = {{0.f,0.f,0.f,0.f},{0.f,0.f,0.f,0.f},{0.f,0.f,0.f,0.f},{0.f,0.f,0.f,0.f}};
    float aI[4][4] = {{0.f,0.f,0.f,0.f},{0.f,0.f,0.f,0.f},{0.f,0.f,0.f,0.f},{0.f,0.f,0.f,0.f}};
    for (int ch = 0; ch < 2; ++ch) {
        __syncthreads();
        #pragma unroll
        for (int j = 0; j < 8; ++j) {
            int l = tid + j * 256;
            int row = l >> 5, i = l & 31;
            long a = base + (long)(r0 + row) * zRow + ch * 32 + i;
            ZRs[row][i] = Z[a];
            ZIs[row][i] = Z[a + 64];
        }
        __syncthreads();
        #pragma unroll
        for (int i2 = 0; i2 < 32; ++i2) {
            int i = ch * 32 + i2;
            float zr[4], zi[4];
            #pragma unroll
            for (int rr = 0; rr < 4; ++rr) {
                zr[rr] = ZRs[ty * 4 + rr][i2];
                zi[rr] = ZIs[ty * 4 + rr][i2];
            }
            float4 wr = *(const float4*)&WRs[i][tx * 4];
            float4 wi = *(const float4*)&WIs[i][tx * 4];
            #pragma unroll
            for (int rr = 0; rr < 4; ++rr) {
                aR[rr][0] += zr[rr] * wr.x - zi[rr] * wi.x;
                aI[rr][0] += zr[rr] * wi.x + zi[rr] * wr.x;
                aR[rr][1] += zr[rr] * wr.y - zi[rr] * wi.y;
                aI[rr][1] += zr[rr] * wi.y + zi[rr] * wr.y;
                aR[rr][2] += zr[rr] * wr.z - zi[rr] * wi.z;
                aI[rr][2] += zr[rr] * wi.z + zi[rr] * wr.z;
                aR[rr][3] += zr[rr] * wr.w - zi[rr] * wi.w;
                aI[rr][3] += zr[rr] * wi.w + zi[rr] * wr.w;
            }
        }
    }
    #pragma unroll
    for (int rr = 0; rr < 4; ++rr) {
        long a = base + (long)(r0 + ty * 4 + rr) * zRow + tx * 4;
        #pragma unroll
        for (int cc = 0; cc < 4; ++cc) {
            L[a + cc] = aR[rr][cc];
            L[a + 64 + cc] = aI[rr][cc];
        }
    }
}

// ------------------------- fused FeedForward + LayerNorm ---------------------
// Per 32-row tile: t1 = relu(R@W0+b0) (staged per 64-col chunk in LDS),
// t = t1@W1 + b1; LN(t); H += ln (or H = gelu(ln) on last layer).
__global__ __launch_bounds__(256) void k_ff(
    const float* __restrict__ R, const float* __restrict__ W0,
    const float* __restrict__ b0v, const float* __restrict__ W1,
    const float* __restrict__ b1v, const float* __restrict__ g1,
    const float* __restrict__ be1, float* __restrict__ H, int last)
{
    __shared__ float Rs[32][68];
    __shared__ float Ts[32][68];
    __shared__ float Was[64][64];
    __shared__ float Wbs[64][64];
    int m0 = blockIdx.x * 32;
    int tid = threadIdx.x, ty = tid >> 4, tx = tid & 15;   // rows ty*2+rr
    #pragma unroll
    for (int j = 0; j < 8; ++j) {
        int l = tid + j * 256;
        int mm = l >> 6, kk = l & 63;
        Rs[mm][kk] = R[(long)(m0 + mm) * 64 + kk];
    }
    float acc2[2][4] = {{0.f,0.f,0.f,0.f},{0.f,0.f,0.f,0.f}};
    for (int nc = 0; nc < 4; ++nc) {
        __syncthreads();
        #pragma unroll
        for (int j = 0; j < 16; ++j) {
            int l = tid + j * 256;
            int kk = l >> 6, nn = l & 63;
            Was[kk][nn] = W0[kk * 256 + nc * 64 + nn];
            Wbs[kk][nn] = W1[(nc * 64 + kk) * 64 + nn];
        }
        __syncthreads();
        float acc1[2][4] = {{0.f,0.f,0.f,0.f},{0.f,0.f,0.f,0.f}};
        #pragma unroll
        for (int s4 = 0; s4 < 64; s4 += 4) {
            float ar[2][4];
            #pragma unroll
            for (int rr = 0; rr < 2; ++rr)
                *(float4*)&ar[rr][0] = *(const float4*)&Rs[ty * 2 + rr][s4];
            #pragma unroll
            for (int ss = 0; ss < 4; ++ss) {
                float4 b4 = *(const float4*)&Was[s4 + ss][tx * 4];
                #pragma unroll
                for (int rr = 0; rr < 2; ++rr) {
                    float a = ar[rr][ss];
                    acc1[rr][0] += a * b4.x; acc1[rr][1] += a * b4.y;
                    acc1[rr][2] += a * b4.z; acc1[rr][3] += a * b4.w;
                }
            }
        }
        #pragma unroll
        for (int rr = 0; rr < 2; ++rr) {
            #pragma unroll
            for (int cc = 0; cc < 4; ++cc)
                Ts[ty * 2 + rr][tx * 4 + cc] =
                    fmaxf(acc1[rr][cc] + b0v[nc * 64 + tx * 4 + cc], 0.0f);
        }
        __syncthreads();
        #pragma unroll
        for (int s4 = 0; s4 < 64; s4 += 4) {
            float ar[2][4];
            #pragma unroll
            for (int rr = 0; rr < 2; ++rr)
                *(float4*)&ar[rr][0] = *(const float4*)&Ts[ty * 2 + rr][s4];
            #pragma unroll
            for (int ss = 0; ss < 4; ++ss) {
                float4 b4 = *(const float4*)&Wbs[s4 + ss][tx * 4];
                #pragma unroll
                for (int rr = 0; rr < 2; ++rr) {
                    float a = ar[rr][ss];
                    acc2[rr][0] += a * b4.x; acc2[rr][1] += a * b4.y;
                    acc2[rr][2] += a * b4.z; acc2[rr][3] += a * b4.w;
                }
            }
        }
    }
    float bia[4], gg[4], bb[4];
    #pragma unroll
    for (int cc = 0; cc < 4; ++cc) {
        bia[cc] = b1v[tx * 4 + cc];
        gg[cc]  = g1[tx * 4 + cc];
        bb[cc]  = be1[tx * 4 + cc];
    }
    #pragma unroll
    for (int rr = 0; rr < 2; ++rr) {
        float t0 = acc2[rr][0] + bia[0], t1 = acc2[rr][1] + bia[1];
        float t2 = acc2[rr][2] + bia[2], t3 = acc2[rr][3] + bia[3];
        float s = t0 + t1 + t2 + t3;
        float q = t0 * t0 + t1 * t1 + t2 * t2 + t3 * t3;
        for (int d = 1; d < 16; d <<= 1) {
            s += __shfl_xor(s, d, 64);
            q += __shfl_xor(q, d, 64);
        }
        float mean = s * (1.0f / 64.0f);
        float var = q * (1.0f / 64.0f) - mean * mean;
        float inv = rsqrtf(var + 1e-5f);
        long addr = (long)(m0 + ty * 2 + rr) * 64 + tx * 4;
        float tv[4] = {t0, t1, t2, t3};
        #pragma unroll
        for (int cc = 0; cc < 4; ++cc) {
            float v = (tv[cc] - mean) * inv * gg[cc] + bb[cc];
            if (last) H[addr + cc] = gelu_f(v);
            else      H[addr + cc] += v;
        }
    }
}

// ------------------------- output heads (thread-per-pixel) -------------------
__global__ __launch_bounds__(256) void k_head(
    const float* __restrict__ H, const float* __restrict__ x0,
    const float* __restrict__ fa_w, const float* __restrict__ fa_b,
    const float* __restrict__ fb_w, const float* __restrict__ fb_b,
    const float* __restrict__ c1w, const float* __restrict__ c1b,
    const float* __restrict__ c2w, const float* __restrict__ c2b,
    float* __restrict__ out)
{
    int f = blockIdx.y;
    int tid = threadIdx.x;
    long px = (long)blockIdx.x * 256 + tid;
    __shared__ float Wt[70][64];   // Wt[j][k] = weight for output j, channel k
    __shared__ float bs[70];
    __shared__ float w1s[8][12], b1s[8], w2s[8][12];
    for (int l = tid; l < 4480; l += 256) {
        int j = l >> 6, k = l & 63;
        Wt[j][k] = (j < 36) ? fa_w[(long)f * 2304 + k * 36 + j]
                            : fb_w[(long)f * 2176 + k * 34 + (j - 36)];
    }
    if (tid < 36) bs[tid] = fa_b[f * 36 + tid];
    else if (tid < 70) bs[tid] = fb_b[f * 34 + tid - 36];
    if (tid >= 128 && tid < 224) w1s[(tid - 128) / 12][(tid - 128) % 12] = c1w[f * 96 + tid - 128];
    if (tid >= 96 && tid < 104)  b1s[tid - 96] = c1b[f * 8 + tid - 96];
    if (tid < 96)                w2s[tid / 12][tid % 12] = c2w[f * 96 + tid];
    __syncthreads();
    float4 h4[16];
    const float4* hp = (const float4*)(H + px * 64);
    #pragma unroll
    for (int q = 0; q < 16; ++q) h4[q] = hp[q];
    float ha[70];
    #pragma unroll
    for (int j = 0; j < 70; ++j) {
        float s = bs[j];
        #pragma unroll
        for (int q = 0; q < 16; ++q) {
            float4 w = *(const float4*)&Wt[j][q * 4];
            s += h4[q].x * w.x + h4[q].y * w.y + h4[q].z * w.z + h4[q].w * w.w;
        }
        ha[j] = gelu_f(s);
    }
    float b2v = c2b[f];
    float u2[10];
    #pragma unroll
    for (int d = 0; d < 10; ++d) u2[d] = b2v;
    for (int c = 0; c < 8; ++c) {
        float wr[12], w2r[12];
        #pragma unroll
        for (int t = 0; t < 12; ++t) { wr[t] = w1s[c][t]; w2r[t] = w2s[c][t]; }
        float bc = b1s[c];
        float u1[30];
        #pragma unroll
        for (int p = 0; p < 30; ++p) {
            float s = bc;
            #pragma unroll
            for (int t = 0; t < 12; ++t) s += ha[2 * p + t] * wr[t];
            u1[p] = gelu_f(s);
        }
        #pragma unroll
        for (int p2 = 0; p2 < 10; ++p2) {
            float s = u2[p2];
            #pragma unroll
            for (int t = 0; t < 12; ++t) s += u1[2 * p2 + t] * w2r[t];
            u2[p2] = s;
        }
    }
    float xv = x0[px * 5 + f];
    #pragma unroll
    for (int d = 0; d < 10; ++d)
        out[px * 50 + f * 10 + d] = xv + u2[d] * (float)(d + 1) * 0.1f;
}

// ---------------------------------------------------------------------------
extern "C" void kernel_launch(void* const* d_in, const int* in_sizes, int n_in,
                              void* d_out, int out_size, void* d_ws, size_t ws_size,
                              hipStream_t stream) {
    (void)in_sizes; (void)n_in; (void)out_size; (void)ws_size;
    const float* xin    = (const float*)d_in[0];
    const float* params = (const float*)d_in[1];
    const float* in_w   = (const float*)d_in[2];
    const float* in_b   = (const float*)d_in[3];
    const float* fnu_w1 = (const float*)d_in[4];
    const float* fnu_b1 = (const float*)d_in[5];
    const float* fnu_w2 = (const float*)d_in[6];
    const float* fnu_b2 = (const float*)d_in[7];
    const float* fnu_w3 = (const float*)d_in[8];
    const float* fnu_b3 = (const float*)d_in[9];
    const float* fw_y   = (const float*)d_in[10];
    const float* fw_x   = (const float*)d_in[11];
    const float* ff_w0  = (const float*)d_in[12];
    const float* ff_b0  = (const float*)d_in[13];
    const float* ff_w1  = (const float*)d_in[14];
    const float* ff_b1  = (const float*)d_in[15];
    const float* ln_g   = (const float*)d_in[16];
    const float* ln_b   = (const float*)d_in[17];
    const float* fa_w   = (const float*)d_in[18];
    const float* fa_b   = (const float*)d_in[19];
    const float* fb_w   = (const float*)d_in[20];
    const float* fb_b   = (const float*)d_in[21];
    const float* c1_w   = (const float*)d_in[22];
    const float* c1_b   = (const float*)d_in[23];
    const float* c2_w   = (const float*)d_in[24];
    const float* c2_b   = (const float*)d_in[25];
    float* out = (float*)d_out;
    float* ws  = (float*)d_ws;

    float* tab   = ws;                 // 131072
    float* tabYF = ws + 0;
    float* tabXF = ws + 32768;
    float* tabYI = ws + 65536;
    float* tabXI = ws + 98304;
    float* att   = ws + 131072;        // 64
    float* H     = ws + 131136;        // 16777216  [b][x][y][ch]
    float* WRb   = ws + 16908352;      // 1048576
    float* WIb   = ws + 17956928;      // 1048576
    float* Zb    = ws + 19005504;      // 8388608  (Z, mix in-place)
    float* Rb    = ws + 27394112;      // 16777216 [b][x][y][ch]

    k_tables<<<512, 256, 0, stream>>>(tab);
    k_att<<<1, 128, 0, stream>>>(params, fnu_w1, fnu_b1, fnu_w2, fnu_b2, fnu_w3, fnu_b3, att);
    k_embed<<<65536, 256, 0, stream>>>(xin, in_w, in_b, H);

    for (int lay = 0; lay < 4; ++lay) {
        const float* attL = att + lay * 16;
        // -------- Y branch (periodic rfft) --------
        k_wgen<<<dim3(64, 4), 256, 0, stream>>>(fw_y + (long)lay * 2097152, attL, WRb, WIb);
        gemm64<<<dim3(1, 2, 1024), 256, 0, stream>>>(
            tabYF, 256,
            H, 4194304L, 16384L, 128, 64,
            Zb, 2097152L, 8192L, 128, 64,
            8, 256, nullptr, 0);
        k_mix<<<dim3(4, 256), 256, 0, stream>>>(Zb, WRb, WIb, Zb, 2097152L, 128L, 8192);
        gemm64<<<dim3(1, 4, 1024), 256, 0, stream>>>(
            tabYI, 128,
            Zb, 2097152L, 8192L, 128, 64,
            Rb, 4194304L, 16384L, 128, 64,
            8, 128, nullptr, 0);
        // -------- X branch (Dirichlet DST) --------
        k_wgen<<<dim3(64, 4), 256, 0, stream>>>(fw_x + (long)lay * 2097152, attL, WRb, WIb);
        gemm64<<<dim3(1, 2, 1024), 256, 0, stream>>>(
            tabXF, 256,
            H, 4194304L, 64L, 32768, 16384,
            Zb, 2097152L, 128L, 32768, 64,
            8, 256, nullptr, 0);
        k_mix<<<dim3(4, 256), 256, 0, stream>>>(Zb, WRb, WIb, Zb, 2097152L, 32768L, 128);
        gemm64<<<dim3(1, 4, 1024), 256, 0, stream>>>(
            tabXI, 128,
            Zb, 2097152L, 128L, 32768, 64,
            Rb, 4194304L, 64L, 32768, 16384,
            8, 128, nullptr, 2);           // accumulate xx into xy
        // -------- fused FeedForward + LN (+residual / final gelu) --------
        k_ff<<<8192, 256, 0, stream>>>(
            Rb, ff_w0 + (long)lay * 16384, ff_b0 + lay * 256,
            ff_w1 + (long)lay * 16384, ff_b1 + lay * 64,
            ln_g + lay * 64, ln_b + lay * 64,
            H, (lay == 3) ? 1 : 0);
    }
    k_head<<<dim3(1024, 5), 256, 0, stream>>>(H, xin, fa_w, fa_b, fb_w, fb_b,
                                              c1_w, c1_b, c2_w, c2_b, out);
}

// Round 4
// 3096.602 us; speedup vs baseline: 2.0777x; 1.4751x over previous
//
#include <hip/hip_runtime.h>
#include <math.h>

// ---------------------------------------------------------------------------
// OmniFluids2D forward on MI355X. bf16-MFMA for all GEMM-shaped work
// (spectral transforms, FF, head ha-GEMM); fp32 elsewhere.
// B=4, NX=NY=256, W=64, L=4, modes=64, NF=5, ODIM=10.
// ---------------------------------------------------------------------------

typedef __attribute__((ext_vector_type(8))) short sh8;
typedef __attribute__((ext_vector_type(4))) float f4;

__device__ __forceinline__ float gelu_f(float v) {
    return 0.5f * v * (1.0f + erff(v * 0.70710678118654752f));
}
__device__ __forceinline__ unsigned short f2bf(float x) {
    unsigned int u = __float_as_uint(x);
    u += 0x7fffu + ((u >> 16) & 1u);
    return (unsigned short)(u >> 16);
}
__device__ __forceinline__ float bf2f(unsigned short h) {
    return __uint_as_float(((unsigned int)h) << 16);
}

// ------------------------- trig tables (bf16) -------------------------------
__global__ void k_tables(unsigned short* __restrict__ tabBf) {
    int idx = blockIdx.x * 256 + threadIdx.x;   // 0..131071
    int t = idx >> 15;
    int r = idx & 32767;
    const double PI = 3.14159265358979323846;
    const double s510 = 1.0 / sqrt(510.0);
    double v = 0.0;
    if (t == 0) {            // TAB_YF [row=2m+c][y]  (128x256)
        int row = r >> 8, y = r & 255;
        int m = row >> 1, c = row & 1;
        double ang = 2.0 * PI * (double)(m * y) / 256.0;
        v = (c == 0 ? cos(ang) : -sin(ang)) / 16.0;
    } else if (t == 1) {     // TAB_XF [row=2k+c][x]  (128x256)
        int row = r >> 8, xx = r & 255;
        int k = row >> 1, c = row & 1;
        if (c == 0) {
            v = 0.0;
            if (xx == 0)   v = s510;
            if (xx == 255) v = (k & 1) ? -s510 : s510;
        } else {
            double ang = PI * (double)(k * xx) / 255.0;
            v = -2.0 * s510 * sin(ang);
        }
    } else if (t == 2) {     // TAB_YI [y][row=2m+c]  (256x128)
        int y = r >> 7, row = r & 127;
        int m = row >> 1, c = row & 1;
        double ang = 2.0 * PI * (double)(m * y) / 256.0;
        if (c == 0) v = (m == 0 ? 1.0 : 2.0 * cos(ang)) / 16.0;
        else        v = (m == 0 ? 0.0 : -2.0 * sin(ang) / 16.0);
    } else {                 // TAB_XI [x][row=2k+c]  (256x128)
        int xx = r >> 7, row = r & 127;
        int k = row >> 1, c = row & 1;
        double ang = PI * (double)(k * xx) / 255.0;
        if (c == 0) v = s510 * (k == 0 ? 1.0 : 2.0 * cos(ang));
        else        v = (k == 0 ? 0.0 : -2.0 * s510 * sin(ang));
    }
    tabBf[idx] = f2bf((float)v);
}

// ------------------------- weight conversion ---------------------------------
// W0T[l][n(256)][k(64)], W1T[l][n(64)][k(256)], Wcat[f][n(80)][k(64)], bcat[f][80]
__global__ void k_cvtw(const float* __restrict__ ff_w0, const float* __restrict__ ff_w1,
                       const float* __restrict__ fa_w, const float* __restrict__ fb_w,
                       const float* __restrict__ fa_b, const float* __restrict__ fb_b,
                       unsigned short* __restrict__ W0T, unsigned short* __restrict__ W1T,
                       unsigned short* __restrict__ Wcat, float* __restrict__ bcat) {
    int idx = blockIdx.x * 256 + threadIdx.x;
    if (idx < 65536) {
        int l = idx >> 14, rem = idx & 16383;
        int n = rem >> 6, k = rem & 63;
        W0T[idx] = f2bf(ff_w0[l * 16384 + k * 256 + n]);
    } else if (idx < 131072) {
        int j = idx - 65536;
        int l = j >> 14, rem = j & 16383;
        int n = rem >> 8, k = rem & 255;
        W1T[j] = f2bf(ff_w1[l * 16384 + k * 64 + n]);
    } else if (idx < 156672) {
        int j = idx - 131072;
        int f = j / 5120, r2 = j % 5120;
        int n = r2 >> 6, k = r2 & 63;
        float v = 0.0f;
        if (n < 36)      v = fa_w[f * 2304 + k * 36 + n];
        else if (n < 70) v = fb_w[f * 2176 + k * 34 + (n - 36)];
        Wcat[j] = f2bf(v);
    } else if (idx < 157072) {
        int j = idx - 156672;
        int f = j / 80, n = j % 80;
        float v = 0.0f;
        if (n < 36)      v = fa_b[f * 36 + n];
        else if (n < 70) v = fb_b[f * 34 + (n - 36)];
        bcat[j] = v;
    }
}

// ------------------------- routing attention --------------------------------
__global__ void k_att(const float* __restrict__ params,
                      const float* __restrict__ w1, const float* __restrict__ b1,
                      const float* __restrict__ w2, const float* __restrict__ b2,
                      const float* __restrict__ w3, const float* __restrict__ b3,
                      float* __restrict__ att) {
    __shared__ float A1[128], A2[128], LG[4];
    int j = threadIdx.x;   // 128 threads
    for (int lay = 0; lay < 4; ++lay)
    for (int b = 0; b < 4; ++b) {
        float s = b1[lay * 128 + j];
        for (int p = 0; p < 8; ++p) s += params[b * 8 + p] * w1[(lay * 8 + p) * 128 + j];
        A1[j] = gelu_f(s);
        __syncthreads();
        s = b2[lay * 128 + j];
        for (int q = 0; q < 128; ++q) s += A1[q] * w2[(lay * 128 + q) * 128 + j];
        A2[j] = gelu_f(s);
        __syncthreads();
        if (j < 4) {
            float tacc = b3[lay * 4 + j];
            for (int q = 0; q < 128; ++q) tacc += A2[q] * w3[(lay * 128 + q) * 4 + j];
            LG[j] = tacc * 0.1f;
        }
        __syncthreads();
        if (j == 0) {
            float mx = fmaxf(fmaxf(LG[0], LG[1]), fmaxf(LG[2], LG[3]));
            float e0 = expf(LG[0] - mx), e1 = expf(LG[1] - mx);
            float e2 = expf(LG[2] - mx), e3 = expf(LG[3] - mx);
            float inv = 1.0f / (e0 + e1 + e2 + e3);
            att[lay * 16 + b * 4 + 0] = e0 * inv;
            att[lay * 16 + b * 4 + 1] = e1 * inv;
            att[lay * 16 + b * 4 + 2] = e2 * inv;
            att[lay * 16 + b * 4 + 3] = e3 * inv;
        }
        __syncthreads();
    }
}

// ------------------------- input embedding ----------------------------------
__global__ __launch_bounds__(256) void k_embed(const float* __restrict__ xin,
                        const float* __restrict__ inw,
                        const float* __restrict__ inb, float* __restrict__ H) {
    long gid = (long)blockIdx.x * 256 + threadIdx.x;
    long px = gid >> 6;
    int ch = (int)(gid & 63);
    int y = (int)(px & 255), xi = (int)((px >> 8) & 255);
    const float* xp = xin + px * 5;
    float v[7];
    v[0] = xp[0]; v[1] = xp[1]; v[2] = xp[2]; v[3] = xp[3]; v[4] = xp[4];
    const float STEP = 6.283185307179586f / 256.0f;
    v[5] = xi * STEP;
    v[6] = y * STEP;
    float s = inb[ch];
    #pragma unroll
    for (int p = 0; p < 7; ++p) s += v[p] * inw[p * 64 + ch];
    H[gid] = gelu_f(s);
}

// ------------------------- per-layer W generation ---------------------------
__global__ __launch_bounds__(256) void k_wgen(const float* __restrict__ fw,
                       const float* __restrict__ att,   // + lay*16
                       float* __restrict__ WRo, float* __restrict__ WIo) {
    int ii = blockIdx.x;   // 64 (channel i)
    int b  = blockIdx.y;   // 4
    int tid = threadIdx.x;
    float av[4];
    av[0] = att[b * 4 + 0]; av[1] = att[b * 4 + 1];
    av[2] = att[b * 4 + 2]; av[3] = att[b * 4 + 3];
    float acc[32];
    #pragma unroll
    for (int j = 0; j < 32; ++j) acc[j] = 0.0f;
    const float* base = fw + (long)ii * 8192;
    for (int k = 0; k < 4; ++k) {
        const float* p = base + (long)k * 524288;
        float a = av[k];
        #pragma unroll
        for (int j = 0; j < 32; ++j) acc[j] += a * p[tid + j * 256];
    }
    __shared__ float ldsR[64 * 65], ldsI[64 * 65];
    #pragma unroll
    for (int j = 0; j < 32; ++j) {
        int l = tid + j * 256;                 // l over [o][m][c]
        int o = l >> 7, m = (l >> 1) & 63, c = l & 1;
        (c ? ldsI : ldsR)[o * 65 + m] = acc[j];
    }
    __syncthreads();
    long ob = (long)b * 262144 + (long)ii * 64;
    for (int w = tid; w < 4096; w += 256) {
        int m = w >> 6, o = w & 63;
        WRo[ob + (long)m * 4096 + o] = ldsR[o * 65 + m];
        WIo[ob + (long)m * 4096 + o] = ldsI[o * 65 + m];
    }
}

// ------------------------- MFMA forward transform ----------------------------
// Per g=(b,s): Z(M=128 modec x N=64 ch) = TAB(128x256) @ h(K=256 x 64).
// B element: H[b*hHi + s*hLo + k*hK + n]; C: Z[b*2097152 + s*zLo +
//            (r>>1)*sMode + (r&1)*64 + ch].
__global__ __launch_bounds__(256) void k_tf(
    const unsigned short* __restrict__ tab, const float* __restrict__ H,
    long hHi, long hLo, int hK, float* __restrict__ Zo, long zLo, int sMode)
{
    __shared__ unsigned short ldsB[64 * 264];
    int g = blockIdx.x;
    int b = g >> 8, s = g & 255;
    int tid = threadIdx.x;
    long hBase = (long)b * hHi + (long)s * hLo;
    #pragma unroll
    for (int it = 0; it < 64; ++it) {
        int idx = tid + it * 256;
        int k = idx >> 6, n = idx & 63;
        ldsB[n * 264 + k] = f2bf(H[hBase + (long)k * hK + n]);
    }
    __syncthreads();
    int w = tid >> 6, lane = tid & 63;
    int q = lane >> 4, ln = lane & 15;
    f4 acc[2][4];
    #pragma unroll
    for (int mi = 0; mi < 2; ++mi)
        #pragma unroll
        for (int ni = 0; ni < 4; ++ni) acc[mi][ni] = (f4){0.f, 0.f, 0.f, 0.f};
    for (int kc = 0; kc < 256; kc += 32) {
        sh8 a[2], bf[4];
        #pragma unroll
        for (int mi = 0; mi < 2; ++mi)
            a[mi] = *(const sh8*)(tab + (w * 32 + mi * 16 + ln) * 256 + kc + q * 8);
        #pragma unroll
        for (int ni = 0; ni < 4; ++ni)
            bf[ni] = *(const sh8*)(ldsB + (ni * 16 + ln) * 264 + kc + q * 8);
        #pragma unroll
        for (int mi = 0; mi < 2; ++mi)
            #pragma unroll
            for (int ni = 0; ni < 4; ++ni)
                acc[mi][ni] = __builtin_amdgcn_mfma_f32_16x16x32_bf16(
                    a[mi], bf[ni], acc[mi][ni], 0, 0, 0);
    }
    long zBase = (long)b * 2097152 + (long)s * zLo;
    #pragma unroll
    for (int mi = 0; mi < 2; ++mi)
        #pragma unroll
        for (int ni = 0; ni < 4; ++ni)
            #pragma unroll
            for (int reg = 0; reg < 4; ++reg) {
                int r = w * 32 + mi * 16 + q * 4 + reg;
                int ch = ni * 16 + ln;
                Zo[zBase + (long)(r >> 1) * sMode + (r & 1) * 64 + ch] = acc[mi][ni][reg];
            }
}

// ------------------------- MFMA inverse transform ----------------------------
// Per g=(b,s): R(M=256 x N=64) = TABI(256x128) @ L(128 x 64), += if accum.
__global__ __launch_bounds__(256) void k_ti(
    const unsigned short* __restrict__ tab, const float* __restrict__ Z,
    long zLo, int sMode, float* __restrict__ Ro, long rLo, int rStride, int accum)
{
    __shared__ unsigned short ldsB[64 * 136];
    int g = blockIdx.x;
    int b = g >> 8, s = g & 255;
    int tid = threadIdx.x;
    long zBase = (long)b * 2097152 + (long)s * zLo;
    #pragma unroll
    for (int it = 0; it < 32; ++it) {
        int idx = tid + it * 256;
        int k = idx >> 6, ch = idx & 63;
        ldsB[ch * 136 + k] = f2bf(Z[zBase + (long)(k >> 1) * sMode + (k & 1) * 64 + ch]);
    }
    __syncthreads();
    int w = tid >> 6, lane = tid & 63;
    int q = lane >> 4, ln = lane & 15;
    f4 acc[4][4];
    #pragma unroll
    for (int mi = 0; mi < 4; ++mi)
        #pragma unroll
        for (int ni = 0; ni < 4; ++ni) acc[mi][ni] = (f4){0.f, 0.f, 0.f, 0.f};
    for (int kc = 0; kc < 128; kc += 32) {
        sh8 a[4], bf[4];
        #pragma unroll
        for (int mi = 0; mi < 4; ++mi)
            a[mi] = *(const sh8*)(tab + (w * 64 + mi * 16 + ln) * 128 + kc + q * 8);
        #pragma unroll
        for (int ni = 0; ni < 4; ++ni)
            bf[ni] = *(const sh8*)(ldsB + (ni * 16 + ln) * 136 + kc + q * 8);
        #pragma unroll
        for (int mi = 0; mi < 4; ++mi)
            #pragma unroll
            for (int ni = 0; ni < 4; ++ni)
                acc[mi][ni] = __builtin_amdgcn_mfma_f32_16x16x32_bf16(
                    a[mi], bf[ni], acc[mi][ni], 0, 0, 0);
    }
    long rBase = (long)b * 4194304 + (long)s * rLo;
    #pragma unroll
    for (int mi = 0; mi < 4; ++mi)
        #pragma unroll
        for (int ni = 0; ni < 4; ++ni)
            #pragma unroll
            for (int reg = 0; reg < 4; ++reg) {
                int r2 = w * 64 + mi * 16 + q * 4 + reg;
                int ch = ni * 16 + ln;
                long addr = rBase + (long)r2 * rStride + ch;
                float v = acc[mi][ni][reg];
                if (accum) v += Ro[addr];
                Ro[addr] = v;
            }
}

// ------------------------- MFMA fused FeedForward + LN -----------------------
// Per wg: 64 rows. T = relu(R@W0+b0) (bf16 in LDS), t = T@W1+b1, LN,
// H += ln (or H = gelu(ln) on last layer). W0T[n(256)][k(64)], W1T[n(64)][k(256)].
__global__ __launch_bounds__(256) void k_ffm(
    const float* __restrict__ R, const unsigned short* __restrict__ W0T,
    const float* __restrict__ b0, const unsigned short* __restrict__ W1T,
    const float* __restrict__ b1, const float* __restrict__ g1,
    const float* __restrict__ be1, float* __restrict__ H, int last)
{
    __shared__ unsigned short A1[64 * 72];
    __shared__ unsigned short T[64 * 264];
    int m0 = blockIdx.x * 64;
    int tid = threadIdx.x;
    #pragma unroll
    for (int it = 0; it < 16; ++it) {
        int idx = tid + it * 256;
        int m = idx >> 6, k = idx & 63;
        A1[m * 72 + k] = f2bf(R[(long)(m0 + m) * 64 + k]);
    }
    __syncthreads();
    int w = tid >> 6, lane = tid & 63;
    int q = lane >> 4, ln = lane & 15;
    // phase 1: rows w*16..w*16+15, full N=256
    {
        f4 acc1[16];
        #pragma unroll
        for (int nt = 0; nt < 16; ++nt) acc1[nt] = (f4){0.f, 0.f, 0.f, 0.f};
        for (int kc = 0; kc < 64; kc += 32) {
            sh8 a = *(const sh8*)(A1 + (w * 16 + ln) * 72 + kc + q * 8);
            #pragma unroll
            for (int nt = 0; nt < 16; ++nt) {
                sh8 bf = *(const sh8*)(W0T + (nt * 16 + ln) * 64 + kc + q * 8);
                acc1[nt] = __builtin_amdgcn_mfma_f32_16x16x32_bf16(a, bf, acc1[nt], 0, 0, 0);
            }
        }
        #pragma unroll
        for (int nt = 0; nt < 16; ++nt) {
            int n = nt * 16 + ln;
            float bias = b0[n];
            #pragma unroll
            for (int reg = 0; reg < 4; ++reg) {
                int m = w * 16 + q * 4 + reg;
                T[m * 264 + n] = f2bf(fmaxf(acc1[nt][reg] + bias, 0.0f));
            }
        }
    }
    // phase 2: same rows; A2 = T rows written by this wave (intra-wave LDS dep)
    f4 acc2[4];
    #pragma unroll
    for (int nt = 0; nt < 4; ++nt) acc2[nt] = (f4){0.f, 0.f, 0.f, 0.f};
    for (int kc = 0; kc < 256; kc += 32) {
        sh8 a = *(const sh8*)(T + (w * 16 + ln) * 264 + kc + q * 8);
        #pragma unroll
        for (int nt = 0; nt < 4; ++nt) {
            sh8 bf = *(const sh8*)(W1T + (nt * 16 + ln) * 256 + kc + q * 8);
            acc2[nt] = __builtin_amdgcn_mfma_f32_16x16x32_bf16(a, bf, acc2[nt], 0, 0, 0);
        }
    }
    float bia[4], gg[4], bb[4];
    #pragma unroll
    for (int nt = 0; nt < 4; ++nt) {
        int n = nt * 16 + ln;
        bia[nt] = b1[n]; gg[nt] = g1[n]; bb[nt] = be1[n];
    }
    #pragma unroll
    for (int reg = 0; reg < 4; ++reg) {
        float t[4];
        float s = 0.f, qs = 0.f;
        #pragma unroll
        for (int nt = 0; nt < 4; ++nt) {
            t[nt] = acc2[nt][reg] + bia[nt];
            s += t[nt]; qs += t[nt] * t[nt];
        }
        #pragma unroll
        for (int d = 1; d < 16; d <<= 1) {
            s  += __shfl_xor(s, d, 64);
            qs += __shfl_xor(qs, d, 64);
        }
        float mean = s * (1.0f / 64.0f);
        float var  = qs * (1.0f / 64.0f) - mean * mean;
        float inv  = rsqrtf(var + 1e-5f);
        int m = w * 16 + q * 4 + reg;
        long base = (long)(m0 + m) * 64;
        #pragma unroll
        for (int nt = 0; nt < 4; ++nt) {
            int n = nt * 16 + ln;
            float v = (t[nt] - mean) * inv * gg[nt] + bb[nt];
            if (last) H[base + n] = gelu_f(v);
            else      H[base + n] += v;
        }
    }
}

// ------------------------- output heads (MFMA ha + VALU conv) ----------------
__global__ __launch_bounds__(256) void k_headm(
    const float* __restrict__ H, const float* __restrict__ x0,
    const unsigned short* __restrict__ Wcat, const float* __restrict__ bcat,
    const float* __restrict__ c1w, const float* __restrict__ c1b,
    const float* __restrict__ c2w, const float* __restrict__ c2b,
    float* __restrict__ out)
{
    __shared__ unsigned short uL[256 * 90];   // union: As (256x72) then ha (256x90)
    int f = blockIdx.y;
    int tid = threadIdx.x;
    long px0 = (long)blockIdx.x * 256;
    #pragma unroll
    for (int it = 0; it < 64; ++it) {
        int idx = tid + it * 256;
        int m = idx >> 6, k = idx & 63;
        uL[m * 72 + k] = f2bf(H[(px0 + m) * 64 + k]);
    }
    __syncthreads();
    int w = tid >> 6, lane = tid & 63;
    int q = lane >> 4, ln = lane & 15;
    f4 acc[4][5];
    #pragma unroll
    for (int mi = 0; mi < 4; ++mi)
        #pragma unroll
        for (int nt = 0; nt < 5; ++nt) acc[mi][nt] = (f4){0.f, 0.f, 0.f, 0.f};
    for (int kc = 0; kc < 64; kc += 32) {
        sh8 a[4], bf[5];
        #pragma unroll
        for (int mi = 0; mi < 4; ++mi)
            a[mi] = *(const sh8*)(uL + (w * 64 + mi * 16 + ln) * 72 + kc + q * 8);
        #pragma unroll
        for (int nt = 0; nt < 5; ++nt)
            bf[nt] = *(const sh8*)(Wcat + f * 5120 + (nt * 16 + ln) * 64 + kc + q * 8);
        #pragma unroll
        for (int mi = 0; mi < 4; ++mi)
            #pragma unroll
            for (int nt = 0; nt < 5; ++nt)
                acc[mi][nt] = __builtin_amdgcn_mfma_f32_16x16x32_bf16(
                    a[mi], bf[nt], acc[mi][nt], 0, 0, 0);
    }
    __syncthreads();   // all waves done reading As before ha overwrites
    #pragma unroll
    for (int nt = 0; nt < 5; ++nt) {
        int n = nt * 16 + ln;
        if (n < 70) {
            float bias = bcat[f * 80 + n];
            #pragma unroll
            for (int mi = 0; mi < 4; ++mi)
                #pragma unroll
                for (int reg = 0; reg < 4; ++reg) {
                    int m = w * 64 + mi * 16 + q * 4 + reg;
                    uL[m * 90 + n] = f2bf(gelu_f(acc[mi][nt][reg] + bias));
                }
        }
    }
    __syncthreads();
    // conv phase: one pixel per thread
    float hv[70];
    #pragma unroll
    for (int j = 0; j < 70; ++j) hv[j] = bf2f(uL[tid * 90 + j]);
    float b2v = c2b[f];
    float u2[10];
    #pragma unroll
    for (int d = 0; d < 10; ++d) u2[d] = b2v;
    for (int c = 0; c < 8; ++c) {
        float wr[12], w2r[12];
        #pragma unroll
        for (int t = 0; t < 12; ++t) {
            wr[t]  = c1w[f * 96 + c * 12 + t];
            w2r[t] = c2w[f * 96 + c * 12 + t];
        }
        float bc = c1b[f * 8 + c];
        float u1[30];
        #pragma unroll
        for (int p = 0; p < 30; ++p) {
            float s = bc;
            #pragma unroll
            for (int t = 0; t < 12; ++t) s += hv[2 * p + t] * wr[t];
            u1[p] = gelu_f(s);
        }
        #pragma unroll
        for (int p2 = 0; p2 < 10; ++p2) {
            float s = u2[p2];
            #pragma unroll
            for (int t = 0; t < 12; ++t) s += u1[2 * p2 + t] * w2r[t];
            u2[p2] = s;
        }
    }
    long px = px0 + tid;
    float xv = x0[px * 5 + f];
    #pragma unroll
    for (int d = 0; d < 10; ++d)
        out[px * 50 + f * 10 + d] = xv + u2[d] * (float)(d + 1) * 0.1f;
}

// ------------------------- complex mode-mix (fp32, in-place) -----------------
__global__ __launch_bounds__(256) void k_mix(
    const float* Z, const float* __restrict__ WR, const float* __restrict__ WI,
    float* L, long zHi, long zM, int zRow)
{
    int rt = blockIdx.x, g = blockIdx.y;
    int b = g >> 6, mk = g & 63;
    long base = (long)b * zHi + (long)mk * zM;
    long wb = (long)b * 262144 + (long)mk * 4096;
    __shared__ float WRs[64][64], WIs[64][64];
    __shared__ float ZRs[64][33], ZIs[64][33];
    int tid = threadIdx.x, ty = tid >> 4, tx = tid & 15;
    #pragma unroll
    for (int j = 0; j < 16; ++j) {
        int l = tid + j * 256;
        WRs[l >> 6][l & 63] = WR[wb + l];
        WIs[l >> 6][l & 63] = WI[wb + l];
    }
    int r0 = rt * 64;
    float aR[4][4] = {{0.f,0.f,0.f,0.f},{0.f,0.f,0.f,0.f},{0.f,0.f,0.f,0.f},{0.f,0.f,0.f,0.f}};
    float aI[4][4] = {{0.f,0.f,0.f,0.f},{0.f,0.f,0.f,0.f},{0.f,0.f,0.f,0.f},{0.f,0.f,0.f,0.f}};
    for (int ch = 0; ch < 2; ++ch) {
        __syncthreads();
        #pragma unroll
        for (int j = 0; j < 8; ++j) {
            int l = tid + j * 256;
            int row = l >> 5, i = l & 31;
            long a = base + (long)(r0 + row) * zRow + ch * 32 + i;
            ZRs[row][i] = Z[a];
            ZIs[row][i] = Z[a + 64];
        }
        __syncthreads();
        #pragma unroll
        for (int i2 = 0; i2 < 32; ++i2) {
            int i = ch * 32 + i2;
            float zr[4], zi[4];
            #pragma unroll
            for (int rr = 0; rr < 4; ++rr) {
                zr[rr] = ZRs[ty * 4 + rr][i2];
                zi[rr] = ZIs[ty * 4 + rr][i2];
            }
            float4 wr = *(const float4*)&WRs[i][tx * 4];
            float4 wi = *(const float4*)&WIs[i][tx * 4];
            #pragma unroll
            for (int rr = 0; rr < 4; ++rr) {
                aR[rr][0] += zr[rr] * wr.x - zi[rr] * wi.x;
                aI[rr][0] += zr[rr] * wi.x + zi[rr] * wr.x;
                aR[rr][1] += zr[rr] * wr.y - zi[rr] * wi.y;
                aI[rr][1] += zr[rr] * wi.y + zi[rr] * wr.y;
                aR[rr][2] += zr[rr] * wr.z - zi[rr] * wi.z;
                aI[rr][2] += zr[rr] * wi.z + zi[rr] * wr.z;
                aR[rr][3] += zr[rr] * wr.w - zi[rr] * wi.w;
                aI[rr][3] += zr[rr] * wi.w + zi[rr] * wr.w;
            }
        }
    }
    #pragma unroll
    for (int rr = 0; rr < 4; ++rr) {
        long a = base + (long)(r0 + ty * 4 + rr) * zRow + tx * 4;
        #pragma unroll
        for (int cc = 0; cc < 4; ++cc) {
            L[a + cc] = aR[rr][cc];
            L[a + 64 + cc] = aI[rr][cc];
        }
    }
}

// ---------------------------------------------------------------------------
extern "C" void kernel_launch(void* const* d_in, const int* in_sizes, int n_in,
                              void* d_out, int out_size, void* d_ws, size_t ws_size,
                              hipStream_t stream) {
    (void)in_sizes; (void)n_in; (void)out_size; (void)ws_size;
    const float* xin    = (const float*)d_in[0];
    const float* params = (const float*)d_in[1];
    const float* in_w   = (const float*)d_in[2];
    const float* in_b   = (const float*)d_in[3];
    const float* fnu_w1 = (const float*)d_in[4];
    const float* fnu_b1 = (const float*)d_in[5];
    const float* fnu_w2 = (const float*)d_in[6];
    const float* fnu_b2 = (const float*)d_in[7];
    const float* fnu_w3 = (const float*)d_in[8];
    const float* fnu_b3 = (const float*)d_in[9];
    const float* fw_y   = (const float*)d_in[10];
    const float* fw_x   = (const float*)d_in[11];
    const float* ff_w0  = (const float*)d_in[12];
    const float* ff_b0  = (const float*)d_in[13];
    const float* ff_w1  = (const float*)d_in[14];
    const float* ff_b1  = (const float*)d_in[15];
    const float* ln_g   = (const float*)d_in[16];
    const float* ln_b   = (const float*)d_in[17];
    const float* fa_w   = (const float*)d_in[18];
    const float* fa_b   = (const float*)d_in[19];
    const float* fb_w   = (const float*)d_in[20];
    const float* fb_b   = (const float*)d_in[21];
    const float* c1_w   = (const float*)d_in[22];
    const float* c1_b   = (const float*)d_in[23];
    const float* c2_w   = (const float*)d_in[24];
    const float* c2_b   = (const float*)d_in[25];
    float* out = (float*)d_out;
    float* ws  = (float*)d_ws;

    // workspace layout (float offsets); total 44,184,576 floats (~177 MB)
    unsigned short* tabBf  = (unsigned short*)(ws + 0);        // 131072 bf16
    unsigned short* tabYF  = tabBf;
    unsigned short* tabXF  = tabBf + 32768;
    unsigned short* tabYI  = tabBf + 65536;
    unsigned short* tabXI  = tabBf + 98304;
    unsigned short* W0T    = (unsigned short*)(ws + 65536);    // 65536 bf16
    unsigned short* W1T    = (unsigned short*)(ws + 98304);    // 65536 bf16
    unsigned short* Wcat   = (unsigned short*)(ws + 131072);   // 25600 bf16
    float* bcat = ws + 143872;        // 400
    float* att  = ws + 144272;        // 64
    float* H    = ws + 144384;        // 16777216  [b][x][y][ch]
    float* WRb  = ws + 16921600;      // 1048576
    float* WIb  = ws + 17970176;      // 1048576
    float* Zb   = ws + 19018752;      // 8388608  (Z, mix in-place)
    float* Rb   = ws + 27407360;      // 16777216 [b][x][y][ch]

    k_tables<<<512, 256, 0, stream>>>(tabBf);
    k_cvtw<<<614, 256, 0, stream>>>(ff_w0, ff_w1, fa_w, fb_w, fa_b, fb_b,
                                    W0T, W1T, Wcat, bcat);
    k_att<<<1, 128, 0, stream>>>(params, fnu_w1, fnu_b1, fnu_w2, fnu_b2, fnu_w3, fnu_b3, att);
    k_embed<<<65536, 256, 0, stream>>>(xin, in_w, in_b, H);

    for (int lay = 0; lay < 4; ++lay) {
        const float* attL = att + lay * 16;
        // -------- Y branch (periodic rfft) --------
        k_wgen<<<dim3(64, 4), 256, 0, stream>>>(fw_y + (long)lay * 2097152, attL, WRb, WIb);
        k_tf<<<1024, 256, 0, stream>>>(tabYF, H, 4194304L, 16384L, 64, Zb, 8192L, 128);
        k_mix<<<dim3(4, 256), 256, 0, stream>>>(Zb, WRb, WIb, Zb, 2097152L, 128L, 8192);
        k_ti<<<1024, 256, 0, stream>>>(tabYI, Zb, 8192L, 128, Rb, 16384L, 64, 0);
        // -------- X branch (Dirichlet DST) --------
        k_wgen<<<dim3(64, 4), 256, 0, stream>>>(fw_x + (long)lay * 2097152, attL, WRb, WIb);
        k_tf<<<1024, 256, 0, stream>>>(tabXF, H, 4194304L, 64L, 16384, Zb, 128L, 32768);
        k_mix<<<dim3(4, 256), 256, 0, stream>>>(Zb, WRb, WIb, Zb, 2097152L, 32768L, 128);
        k_ti<<<1024, 256, 0, stream>>>(tabXI, Zb, 128L, 32768, Rb, 64L, 16384, 1);
        // -------- fused FeedForward + LN (+residual / final gelu) --------
        k_ffm<<<4096, 256, 0, stream>>>(
            Rb, W0T + lay * 16384, ff_b0 + lay * 256,
            W1T + lay * 16384, ff_b1 + lay * 64,
            ln_g + lay * 64, ln_b + lay * 64,
            H, (lay == 3) ? 1 : 0);
    }
    k_headm<<<dim3(1024, 5), 256, 0, stream>>>(H, xin, Wcat, bcat,
                                               c1_w, c1_b, c2_w, c2_b, out);
}

// Round 5
// 2093.659 us; speedup vs baseline: 3.0730x; 1.4790x over previous
//
#include <hip/hip_runtime.h>
#include <math.h>

// ---------------------------------------------------------------------------
// OmniFluids2D forward on MI355X. bf16 dataflow + MFMA for all GEMM work
// (spectral transforms, mode-mix, FF, head). B=4, 256x256, W=64, L=4, K=64.
// ---------------------------------------------------------------------------

typedef __attribute__((ext_vector_type(8))) short sh8;
typedef __attribute__((ext_vector_type(4))) float f4;

__device__ __forceinline__ float gelu_f(float v) {          // exact (att only)
    return 0.5f * v * (1.0f + erff(v * 0.70710678118654752f));
}
__device__ __forceinline__ float gelu_fast(float v) {       // tanh-approx
    float s = v * (1.5957691216f + 0.0713548162f * v * v);
    return v / (1.0f + __expf(-s));
}
__device__ __forceinline__ unsigned short f2bf(float x) {
    unsigned int u = __float_as_uint(x);
    u += 0x7fffu + ((u >> 16) & 1u);
    return (unsigned short)(u >> 16);
}
__device__ __forceinline__ float bf2f(unsigned short h) {
    return __uint_as_float(((unsigned int)h) << 16);
}

// ------------------------- trig tables (bf16) -------------------------------
__global__ void k_tables(unsigned short* __restrict__ tabBf) {
    int idx = blockIdx.x * 256 + threadIdx.x;   // 0..131071
    int t = idx >> 15;
    int r = idx & 32767;
    const double PI = 3.14159265358979323846;
    const double s510 = 1.0 / sqrt(510.0);
    double v = 0.0;
    if (t == 0) {            // TAB_YF [row=2m+c][y]  (128x256)
        int row = r >> 8, y = r & 255;
        int m = row >> 1, c = row & 1;
        double ang = 2.0 * PI * (double)(m * y) / 256.0;
        v = (c == 0 ? cos(ang) : -sin(ang)) / 16.0;
    } else if (t == 1) {     // TAB_XF [row=2k+c][x]  (128x256)
        int row = r >> 8, xx = r & 255;
        int k = row >> 1, c = row & 1;
        if (c == 0) {
            v = 0.0;
            if (xx == 0)   v = s510;
            if (xx == 255) v = (k & 1) ? -s510 : s510;
        } else {
            double ang = PI * (double)(k * xx) / 255.0;
            v = -2.0 * s510 * sin(ang);
        }
    } else if (t == 2) {     // TAB_YI [y][row=2m+c]  (256x128)
        int y = r >> 7, row = r & 127;
        int m = row >> 1, c = row & 1;
        double ang = 2.0 * PI * (double)(m * y) / 256.0;
        if (c == 0) v = (m == 0 ? 1.0 : 2.0 * cos(ang)) / 16.0;
        else        v = (m == 0 ? 0.0 : -2.0 * sin(ang) / 16.0);
    } else {                 // TAB_XI [x][row=2k+c]  (256x128)
        int xx = r >> 7, row = r & 127;
        int k = row >> 1, c = row & 1;
        double ang = PI * (double)(k * xx) / 255.0;
        if (c == 0) v = s510 * (k == 0 ? 1.0 : 2.0 * cos(ang));
        else        v = (k == 0 ? 0.0 : -2.0 * s510 * sin(ang));
    }
    tabBf[idx] = f2bf((float)v);
}

// ------------------------- weight conversion ---------------------------------
__global__ void k_cvtw(const float* __restrict__ ff_w0, const float* __restrict__ ff_w1,
                       const float* __restrict__ fa_w, const float* __restrict__ fb_w,
                       const float* __restrict__ fa_b, const float* __restrict__ fb_b,
                       unsigned short* __restrict__ W0T, unsigned short* __restrict__ W1T,
                       unsigned short* __restrict__ Wcat, float* __restrict__ bcat) {
    int idx = blockIdx.x * 256 + threadIdx.x;
    if (idx < 65536) {
        int l = idx >> 14, rem = idx & 16383;
        int n = rem >> 6, k = rem & 63;
        W0T[idx] = f2bf(ff_w0[l * 16384 + k * 256 + n]);
    } else if (idx < 131072) {
        int j = idx - 65536;
        int l = j >> 14, rem = j & 16383;
        int n = rem >> 8, k = rem & 255;
        W1T[j] = f2bf(ff_w1[l * 16384 + k * 64 + n]);
    } else if (idx < 156672) {
        int j = idx - 131072;
        int f = j / 5120, r2 = j % 5120;
        int n = r2 >> 6, k = r2 & 63;
        float v = 0.0f;
        if (n < 36)      v = fa_w[f * 2304 + k * 36 + n];
        else if (n < 70) v = fb_w[f * 2176 + k * 34 + (n - 36)];
        Wcat[j] = f2bf(v);
    } else if (idx < 157072) {
        int j = idx - 156672;
        int f = j / 80, n = j % 80;
        float v = 0.0f;
        if (n < 36)      v = fa_b[f * 36 + n];
        else if (n < 70) v = fb_b[f * 34 + (n - 36)];
        bcat[j] = v;
    }
}

// ------------------------- routing attention --------------------------------
__global__ void k_att(const float* __restrict__ params,
                      const float* __restrict__ w1, const float* __restrict__ b1,
                      const float* __restrict__ w2, const float* __restrict__ b2,
                      const float* __restrict__ w3, const float* __restrict__ b3,
                      float* __restrict__ att) {
    __shared__ float A1[128], A2[128], LG[4];
    int j = threadIdx.x;   // 128 threads
    for (int lay = 0; lay < 4; ++lay)
    for (int b = 0; b < 4; ++b) {
        float s = b1[lay * 128 + j];
        for (int p = 0; p < 8; ++p) s += params[b * 8 + p] * w1[(lay * 8 + p) * 128 + j];
        A1[j] = gelu_f(s);
        __syncthreads();
        s = b2[lay * 128 + j];
        for (int q = 0; q < 128; ++q) s += A1[q] * w2[(lay * 128 + q) * 128 + j];
        A2[j] = gelu_f(s);
        __syncthreads();
        if (j < 4) {
            float tacc = b3[lay * 4 + j];
            for (int q = 0; q < 128; ++q) tacc += A2[q] * w3[(lay * 128 + q) * 4 + j];
            LG[j] = tacc * 0.1f;
        }
        __syncthreads();
        if (j == 0) {
            float mx = fmaxf(fmaxf(LG[0], LG[1]), fmaxf(LG[2], LG[3]));
            float e0 = expf(LG[0] - mx), e1 = expf(LG[1] - mx);
            float e2 = expf(LG[2] - mx), e3 = expf(LG[3] - mx);
            float inv = 1.0f / (e0 + e1 + e2 + e3);
            att[lay * 16 + b * 4 + 0] = e0 * inv;
            att[lay * 16 + b * 4 + 1] = e1 * inv;
            att[lay * 16 + b * 4 + 2] = e2 * inv;
            att[lay * 16 + b * 4 + 3] = e3 * inv;
        }
        __syncthreads();
    }
}

// ------------------------- input embedding (H fp32 + Hbf) --------------------
__global__ __launch_bounds__(256) void k_embed(const float* __restrict__ xin,
                        const float* __restrict__ inw, const float* __restrict__ inb,
                        float* __restrict__ H, unsigned short* __restrict__ Hb) {
    long gid = (long)blockIdx.x * 256 + threadIdx.x;   // 0..4194303
    long px = gid >> 4;
    int c4 = (int)(gid & 15) * 4;
    int y = (int)(px & 255), xi = (int)((px >> 8) & 255);
    const float* xp = xin + px * 5;
    float v[7];
    v[0] = xp[0]; v[1] = xp[1]; v[2] = xp[2]; v[3] = xp[3]; v[4] = xp[4];
    const float STEP = 6.283185307179586f / 256.0f;
    v[5] = xi * STEP;
    v[6] = y * STEP;
    float r[4];
    #pragma unroll
    for (int c = 0; c < 4; ++c) {
        int ch = c4 + c;
        float s = inb[ch];
        #pragma unroll
        for (int p = 0; p < 7; ++p) s += v[p] * inw[p * 64 + ch];
        r[c] = gelu_fast(s);
    }
    *(float4*)&H[px * 64 + c4] = make_float4(r[0], r[1], r[2], r[3]);
    unsigned int u0 = (unsigned int)f2bf(r[0]) | ((unsigned int)f2bf(r[1]) << 16);
    unsigned int u1 = (unsigned int)f2bf(r[2]) | ((unsigned int)f2bf(r[3]) << 16);
    uint2 uu; uu.x = u0; uu.y = u1;
    *(uint2*)(Hb + px * 64 + c4) = uu;
}

// ------------------------- per-layer W generation (fp32 [b][m][i][o]) --------
__global__ __launch_bounds__(256) void k_wgen(const float* __restrict__ fw,
                       const float* __restrict__ att,
                       float* __restrict__ WRo, float* __restrict__ WIo) {
    int ii = blockIdx.x;   // 64 (channel i)
    int b  = blockIdx.y;   // 4
    int tid = threadIdx.x;
    float av[4];
    av[0] = att[b * 4 + 0]; av[1] = att[b * 4 + 1];
    av[2] = att[b * 4 + 2]; av[3] = att[b * 4 + 3];
    float acc[32];
    #pragma unroll
    for (int j = 0; j < 32; ++j) acc[j] = 0.0f;
    const float* base = fw + (long)ii * 8192;
    for (int k = 0; k < 4; ++k) {
        const float* p = base + (long)k * 524288;
        float a = av[k];
        #pragma unroll
        for (int j = 0; j < 32; ++j) acc[j] += a * p[tid + j * 256];
    }
    __shared__ float ldsR[64 * 65], ldsI[64 * 65];
    #pragma unroll
    for (int j = 0; j < 32; ++j) {
        int l = tid + j * 256;                 // l over [o][m][c]
        int o = l >> 7, m = (l >> 1) & 63, c = l & 1;
        (c ? ldsI : ldsR)[o * 65 + m] = acc[j];
    }
    __syncthreads();
    long ob = (long)b * 262144 + (long)ii * 64;
    for (int w = tid; w < 4096; w += 256) {
        int m = w >> 6, o = w & 63;
        WRo[ob + (long)m * 4096 + o] = ldsR[o * 65 + m];
        WIo[ob + (long)m * 4096 + o] = ldsI[o * 65 + m];
    }
}

// ------------------------- W transpose to bf16 [b][m][o][i] ------------------
__global__ __launch_bounds__(256) void k_wtr(
    const float* __restrict__ WR, const float* __restrict__ WI,
    unsigned short* __restrict__ WrT, unsigned short* __restrict__ WiT,
    unsigned short* __restrict__ WinT) {
    __shared__ float lR[64 * 65], lI[64 * 65];
    long base = (long)blockIdx.x * 4096;    // (b*64+m)
    int tid = threadIdx.x;
    #pragma unroll
    for (int it = 0; it < 16; ++it) {
        int l = it * 256 + tid;
        int i = l >> 6, o = l & 63;
        lR[i * 65 + o] = WR[base + l];
        lI[i * 65 + o] = WI[base + l];
    }
    __syncthreads();
    #pragma unroll
    for (int it = 0; it < 16; ++it) {
        int l = it * 256 + tid;
        int o = l >> 6, i = l & 63;
        float rr = lR[i * 65 + o], im = lI[i * 65 + o];
        WrT[base + l]  = f2bf(rr);
        WiT[base + l]  = f2bf(im);
        WinT[base + l] = f2bf(-im);
    }
}

// ------------------------- B^T staging: global rows -> lds[n][k] -------------
// lane-varying LDS column index => <=2-way bank conflicts on b32 writes.
__device__ __forceinline__ void stage_bt(unsigned short* lds, int pitch,
    const unsigned short* src, int rowStride, int K, int tid)
{
    int pairs = K >> 1;
    int tasks = pairs * 8;
    for (int idx = tid; idx < tasks; idx += 256) {
        int p = idx & (pairs - 1);
        int cg = idx / pairs;
        const unsigned short* s0 = src + (long)(2 * p) * rowStride + cg * 8;
        sh8 r0 = *(const sh8*)s0;
        sh8 r1 = *(const sh8*)(s0 + rowStride);
        unsigned short* dbase = lds + cg * 8 * pitch + 2 * p;
        #pragma unroll
        for (int j = 0; j < 8; ++j) {
            unsigned int u = (unsigned int)(unsigned short)r0[j]
                           | ((unsigned int)(unsigned short)r1[j] << 16);
            *(unsigned int*)(dbase + j * pitch) = u;
        }
    }
}

// ------------------------- MFMA forward transform ----------------------------
// Per g=(b,s): Z[r=modec 128][i=ch 64] = TAB(128x256) @ h(256 x 64). Z bf16.
__global__ __launch_bounds__(256) void k_tf(
    const unsigned short* __restrict__ tab, const unsigned short* __restrict__ Hb,
    long sLo, int rowStride, unsigned short* __restrict__ Zo)
{
    __shared__ __align__(16) unsigned short ldsB[64 * 272];
    int g = blockIdx.x, b = g >> 8, s = g & 255;
    int tid = threadIdx.x;
    const unsigned short* src = Hb + (long)b * 4194304 + (long)s * sLo;
    stage_bt(ldsB, 272, src, rowStride, 256, tid);
    __syncthreads();
    int w = tid >> 6, lane = tid & 63, q = lane >> 4, ln = lane & 15;
    f4 acc[2][4];
    #pragma unroll
    for (int mi = 0; mi < 2; ++mi)
        #pragma unroll
        for (int ni = 0; ni < 4; ++ni) acc[mi][ni] = (f4){0.f, 0.f, 0.f, 0.f};
    for (int kc = 0; kc < 256; kc += 32) {
        sh8 a[2], bf[4];
        #pragma unroll
        for (int mi = 0; mi < 2; ++mi)
            a[mi] = *(const sh8*)(tab + (w * 32 + mi * 16 + ln) * 256 + kc + q * 8);
        #pragma unroll
        for (int ni = 0; ni < 4; ++ni)
            bf[ni] = *(const sh8*)(ldsB + (ni * 16 + ln) * 272 + kc + q * 8);
        #pragma unroll
        for (int mi = 0; mi < 2; ++mi)
            #pragma unroll
            for (int ni = 0; ni < 4; ++ni)
                acc[mi][ni] = __builtin_amdgcn_mfma_f32_16x16x32_bf16(
                    a[mi], bf[ni], acc[mi][ni], 0, 0, 0);
    }
    long zB = (long)b * 2097152 + (long)s * 8192;
    #pragma unroll
    for (int mi = 0; mi < 2; ++mi)
        #pragma unroll
        for (int ni = 0; ni < 4; ++ni)
            #pragma unroll
            for (int reg = 0; reg < 4; ++reg) {
                int r = w * 32 + mi * 16 + q * 4 + reg;
                Zo[zB + r * 64 + ni * 16 + ln] = f2bf(acc[mi][ni][reg]);
            }
}

// ------------------------- MFMA complex mode-mix (in-place, no LDS) ----------
// Per (b,m): L[s 256][o 64] = Z[s][i] * W[i][o] (complex), overwrite Z.
__global__ __launch_bounds__(256) void k_mixm(
    unsigned short* Z, const unsigned short* __restrict__ WrT,
    const unsigned short* __restrict__ WiT, const unsigned short* __restrict__ WinT)
{
    int xt = blockIdx.x, g = blockIdx.y;
    int b = g >> 6, m = g & 63;
    int tid = threadIdx.x, w = tid >> 6, lane = tid & 63, q = lane >> 4, ln = lane & 15;
    long zB = (long)b * 2097152 + (long)m * 128;
    long wB = (long)b * 262144 + (long)m * 4096;
    int s0 = xt * 64 + w * 16;
    f4 aR[4], aI[4];
    #pragma unroll
    for (int nt = 0; nt < 4; ++nt) { aR[nt] = (f4){0.f,0.f,0.f,0.f}; aI[nt] = (f4){0.f,0.f,0.f,0.f}; }
    for (int kc = 0; kc < 64; kc += 32) {
        sh8 zr = *(const sh8*)(Z + zB + (long)(s0 + ln) * 8192 + kc + q * 8);
        sh8 zi = *(const sh8*)(Z + zB + (long)(s0 + ln) * 8192 + 64 + kc + q * 8);
        #pragma unroll
        for (int nt = 0; nt < 4; ++nt) {
            int o = nt * 16 + ln;
            sh8 wr = *(const sh8*)(WrT + wB + o * 64 + kc + q * 8);
            sh8 wi = *(const sh8*)(WiT + wB + o * 64 + kc + q * 8);
            sh8 wn = *(const sh8*)(WinT + wB + o * 64 + kc + q * 8);
            aR[nt] = __builtin_amdgcn_mfma_f32_16x16x32_bf16(zr, wr, aR[nt], 0, 0, 0);
            aR[nt] = __builtin_amdgcn_mfma_f32_16x16x32_bf16(zi, wn, aR[nt], 0, 0, 0);
            aI[nt] = __builtin_amdgcn_mfma_f32_16x16x32_bf16(zr, wi, aI[nt], 0, 0, 0);
            aI[nt] = __builtin_amdgcn_mfma_f32_16x16x32_bf16(zi, wr, aI[nt], 0, 0, 0);
        }
    }
    #pragma unroll
    for (int nt = 0; nt < 4; ++nt)
        #pragma unroll
        for (int reg = 0; reg < 4; ++reg) {
            int s = s0 + q * 4 + reg;
            long a = zB + (long)s * 8192 + nt * 16 + ln;
            Z[a]      = f2bf(aR[nt][reg]);
            Z[a + 64] = f2bf(aI[nt][reg]);
        }
}

// ------------------------- MFMA inverse transform ----------------------------
// Per g=(b,s): R[256][64] = TABI(256x128) @ L(128x64); bf16 out, optional accum.
__global__ __launch_bounds__(256) void k_ti(
    const unsigned short* __restrict__ tab, const unsigned short* __restrict__ Zl,
    unsigned short* Ro, long rLo, int rStride, int accum)
{
    __shared__ __align__(16) unsigned short ldsB[64 * 144];
    int g = blockIdx.x, b = g >> 8, s = g & 255;
    int tid = threadIdx.x;
    const unsigned short* src = Zl + (long)b * 2097152 + (long)s * 8192;
    stage_bt(ldsB, 144, src, 64, 128, tid);
    __syncthreads();
    int w = tid >> 6, lane = tid & 63, q = lane >> 4, ln = lane & 15;
    f4 acc[4][4];
    #pragma unroll
    for (int mi = 0; mi < 4; ++mi)
        #pragma unroll
        for (int ni = 0; ni < 4; ++ni) acc[mi][ni] = (f4){0.f, 0.f, 0.f, 0.f};
    for (int kc = 0; kc < 128; kc += 32) {
        sh8 a[4], bf[4];
        #pragma unroll
        for (int mi = 0; mi < 4; ++mi)
            a[mi] = *(const sh8*)(tab + (w * 64 + mi * 16 + ln) * 128 + kc + q * 8);
        #pragma unroll
        for (int ni = 0; ni < 4; ++ni)
            bf[ni] = *(const sh8*)(ldsB + (ni * 16 + ln) * 144 + kc + q * 8);
        #pragma unroll
        for (int mi = 0; mi < 4; ++mi)
            #pragma unroll
            for (int ni = 0; ni < 4; ++ni)
                acc[mi][ni] = __builtin_amdgcn_mfma_f32_16x16x32_bf16(
                    a[mi], bf[ni], acc[mi][ni], 0, 0, 0);
    }
    long rB = (long)b * 4194304 + (long)s * rLo;
    #pragma unroll
    for (int mi = 0; mi < 4; ++mi)
        #pragma unroll
        for (int ni = 0; ni < 4; ++ni)
            #pragma unroll
            for (int reg = 0; reg < 4; ++reg) {
                int r2 = w * 64 + mi * 16 + q * 4 + reg;
                long addr = rB + (long)r2 * rStride + ni * 16 + ln;
                float v = acc[mi][ni][reg];
                if (accum) v += bf2f(Ro[addr]);
                Ro[addr] = f2bf(v);
            }
}

// ------------------------- MFMA fused FeedForward + LN -----------------------
__global__ __launch_bounds__(256) void k_ffm(
    const unsigned short* __restrict__ Rb, const unsigned short* __restrict__ W0T,
    const float* __restrict__ b0, const unsigned short* __restrict__ W1T,
    const float* __restrict__ b1, const float* __restrict__ g1,
    const float* __restrict__ be1, float* __restrict__ H,
    unsigned short* __restrict__ Hb, int last)
{
    __shared__ __align__(16) unsigned short T[64 * 264];
    int m0 = blockIdx.x * 64;
    int tid = threadIdx.x, w = tid >> 6, lane = tid & 63, q = lane >> 4, ln = lane & 15;
    // phase 1: T = relu(R @ W0 + b0), rows w*16..+15, N=256
    {
        f4 acc1[16];
        #pragma unroll
        for (int nt = 0; nt < 16; ++nt) acc1[nt] = (f4){0.f, 0.f, 0.f, 0.f};
        for (int kc = 0; kc < 64; kc += 32) {
            sh8 a = *(const sh8*)(Rb + (long)(m0 + w * 16 + ln) * 64 + kc + q * 8);
            #pragma unroll
            for (int nt = 0; nt < 16; ++nt) {
                sh8 bf = *(const sh8*)(W0T + (nt * 16 + ln) * 64 + kc + q * 8);
                acc1[nt] = __builtin_amdgcn_mfma_f32_16x16x32_bf16(a, bf, acc1[nt], 0, 0, 0);
            }
        }
        #pragma unroll
        for (int nt = 0; nt < 16; ++nt) {
            int n = nt * 16 + ln;
            float bias = b0[n];
            #pragma unroll
            for (int reg = 0; reg < 4; ++reg) {
                int m = w * 16 + q * 4 + reg;
                T[m * 264 + n] = f2bf(fmaxf(acc1[nt][reg] + bias, 0.0f));
            }
        }
    }
    // phase 2 (intra-wave LDS dep): t = T @ W1 + b1, then LN + residual
    f4 acc2[4];
    #pragma unroll
    for (int nt = 0; nt < 4; ++nt) acc2[nt] = (f4){0.f, 0.f, 0.f, 0.f};
    for (int kc = 0; kc < 256; kc += 32) {
        sh8 a = *(const sh8*)(T + (w * 16 + ln) * 264 + kc + q * 8);
        #pragma unroll
        for (int nt = 0; nt < 4; ++nt) {
            sh8 bf = *(const sh8*)(W1T + (nt * 16 + ln) * 256 + kc + q * 8);
            acc2[nt] = __builtin_amdgcn_mfma_f32_16x16x32_bf16(a, bf, acc2[nt], 0, 0, 0);
        }
    }
    float bia[4], gg[4], bb[4];
    #pragma unroll
    for (int nt = 0; nt < 4; ++nt) {
        int n = nt * 16 + ln;
        bia[nt] = b1[n]; gg[nt] = g1[n]; bb[nt] = be1[n];
    }
    #pragma unroll
    for (int reg = 0; reg < 4; ++reg) {
        float t[4];
        float s = 0.f, qs = 0.f;
        #pragma unroll
        for (int nt = 0; nt < 4; ++nt) {
            t[nt] = acc2[nt][reg] + bia[nt];
            s += t[nt]; qs += t[nt] * t[nt];
        }
        #pragma unroll
        for (int d = 1; d < 16; d <<= 1) {
            s  += __shfl_xor(s, d, 64);
            qs += __shfl_xor(qs, d, 64);
        }
        float mean = s * (1.0f / 64.0f);
        float var  = qs * (1.0f / 64.0f) - mean * mean;
        float inv  = rsqrtf(var + 1e-5f);
        int m = w * 16 + q * 4 + reg;
        long base = (long)(m0 + m) * 64;
        #pragma unroll
        for (int nt = 0; nt < 4; ++nt) {
            int n = nt * 16 + ln;
            float v = (t[nt] - mean) * inv * gg[nt] + bb[nt];
            float hv;
            if (last) hv = gelu_fast(v);
            else      hv = H[base + n] + v;
            H[base + n] = hv;
            Hb[base + n] = f2bf(hv);
        }
    }
}

// ------------------------- output heads (f-loop inside) ----------------------
__global__ __launch_bounds__(256) void k_headm(
    const unsigned short* __restrict__ Hb, const float* __restrict__ x0,
    const unsigned short* __restrict__ Wcat, const float* __restrict__ bcat,
    const float* __restrict__ c1w, const float* __restrict__ c1b,
    const float* __restrict__ c2w, const float* __restrict__ c2b,
    float* __restrict__ out)
{
    __shared__ unsigned short ha[70 * 260];   // [j][px], pitch 260
    int tid = threadIdx.x;
    long px0 = (long)blockIdx.x * 256;
    int w = tid >> 6, lane = tid & 63, q = lane >> 4, ln = lane & 15;
    for (int f = 0; f < 5; ++f) {
        f4 acc[4][5];
        #pragma unroll
        for (int mi = 0; mi < 4; ++mi)
            #pragma unroll
            for (int nt = 0; nt < 5; ++nt) acc[mi][nt] = (f4){0.f, 0.f, 0.f, 0.f};
        for (int kc = 0; kc < 64; kc += 32) {
            sh8 a[4], bf[5];
            #pragma unroll
            for (int mi = 0; mi < 4; ++mi)
                a[mi] = *(const sh8*)(Hb + (px0 + w * 64 + mi * 16 + ln) * 64 + kc + q * 8);
            #pragma unroll
            for (int nt = 0; nt < 5; ++nt)
                bf[nt] = *(const sh8*)(Wcat + f * 5120 + (nt * 16 + ln) * 64 + kc + q * 8);
            #pragma unroll
            for (int mi = 0; mi < 4; ++mi)
                #pragma unroll
                for (int nt = 0; nt < 5; ++nt)
                    acc[mi][nt] = __builtin_amdgcn_mfma_f32_16x16x32_bf16(
                        a[mi], bf[nt], acc[mi][nt], 0, 0, 0);
        }
        __syncthreads();   // previous iteration's conv reads done
        #pragma unroll
        for (int nt = 0; nt < 5; ++nt) {
            int n = nt * 16 + ln;
            if (n < 70) {
                float bias = bcat[f * 80 + n];
                #pragma unroll
                for (int mi = 0; mi < 4; ++mi) {
                    #pragma unroll
                    for (int rp = 0; rp < 2; ++rp) {
                        int m = w * 64 + mi * 16 + q * 4 + rp * 2;
                        unsigned int u =
                            (unsigned int)f2bf(gelu_fast(acc[mi][nt][rp * 2] + bias))
                          | ((unsigned int)f2bf(gelu_fast(acc[mi][nt][rp * 2 + 1] + bias)) << 16);
                        *(unsigned int*)(ha + n * 260 + m) = u;
                    }
                }
            }
        }
        __syncthreads();
        // conv phase: one pixel per thread
        float hv[70];
        #pragma unroll
        for (int j = 0; j < 70; ++j) hv[j] = bf2f(ha[j * 260 + tid]);
        float b2v = c2b[f];
        float u2[10];
        #pragma unroll
        for (int d = 0; d < 10; ++d) u2[d] = b2v;
        for (int c = 0; c < 8; ++c) {
            float wr[12], w2r[12];
            #pragma unroll
            for (int t = 0; t < 12; ++t) {
                wr[t]  = c1w[f * 96 + c * 12 + t];
                w2r[t] = c2w[f * 96 + c * 12 + t];
            }
            float bc = c1b[f * 8 + c];
            float u1[30];
            #pragma unroll
            for (int p = 0; p < 30; ++p) {
                float s = bc;
                #pragma unroll
                for (int t = 0; t < 12; ++t) s += hv[2 * p + t] * wr[t];
                u1[p] = gelu_fast(s);
            }
            #pragma unroll
            for (int p2 = 0; p2 < 10; ++p2) {
                float s = u2[p2];
                #pragma unroll
                for (int t = 0; t < 12; ++t) s += u1[2 * p2 + t] * w2r[t];
                u2[p2] = s;
            }
        }
        long px = px0 + tid;
        float xv = x0[px * 5 + f];
        #pragma unroll
        for (int d = 0; d < 10; ++d)
            out[px * 50 + f * 10 + d] = xv + u2[d] * (float)(d + 1) * 0.1f;
    }
}

// ---------------------------------------------------------------------------
extern "C" void kernel_launch(void* const* d_in, const int* in_sizes, int n_in,
                              void* d_out, int out_size, void* d_ws, size_t ws_size,
                              hipStream_t stream) {
    (void)in_sizes; (void)n_in; (void)out_size; (void)ws_size;
    const float* xin    = (const float*)d_in[0];
    const float* params = (const float*)d_in[1];
    const float* in_w   = (const float*)d_in[2];
    const float* in_b   = (const float*)d_in[3];
    const float* fnu_w1 = (const float*)d_in[4];
    const float* fnu_b1 = (const float*)d_in[5];
    const float* fnu_w2 = (const float*)d_in[6];
    const float* fnu_b2 = (const float*)d_in[7];
    const float* fnu_w3 = (const float*)d_in[8];
    const float* fnu_b3 = (const float*)d_in[9];
    const float* fw_y   = (const float*)d_in[10];
    const float* fw_x   = (const float*)d_in[11];
    const float* ff_w0  = (const float*)d_in[12];
    const float* ff_b0  = (const float*)d_in[13];
    const float* ff_w1  = (const float*)d_in[14];
    const float* ff_b1  = (const float*)d_in[15];
    const float* ln_g   = (const float*)d_in[16];
    const float* ln_b   = (const float*)d_in[17];
    const float* fa_w   = (const float*)d_in[18];
    const float* fa_b   = (const float*)d_in[19];
    const float* fb_w   = (const float*)d_in[20];
    const float* fb_b   = (const float*)d_in[21];
    const float* c1_w   = (const float*)d_in[22];
    const float* c1_b   = (const float*)d_in[23];
    const float* c2_w   = (const float*)d_in[24];
    const float* c2_b   = (const float*)d_in[25];
    float* out = (float*)d_out;
    float* ws  = (float*)d_ws;

    // workspace layout (float offsets); total ~37.4M floats (~150 MB)
    unsigned short* tabBf = (unsigned short*)(ws + 0);       // 131072 shorts
    unsigned short* tabYF = tabBf;
    unsigned short* tabXF = tabBf + 32768;
    unsigned short* tabYI = tabBf + 65536;
    unsigned short* tabXI = tabBf + 98304;
    unsigned short* W0T   = (unsigned short*)(ws + 65536);   // 65536 shorts
    unsigned short* W1T   = (unsigned short*)(ws + 98304);   // 65536 shorts
    unsigned short* Wcat  = (unsigned short*)(ws + 131072);  // 25600 shorts
    float* bcat = ws + 143872;                                // 400
    float* att  = ws + 144272;                                // 64
    float* H    = ws + 144384;                                // 16777216
    unsigned short* Hbf = (unsigned short*)(ws + 16921600);  // 16.7M shorts
    float* WRb  = ws + 25310208;                              // 1048576
    float* WIb  = ws + 26358784;                              // 1048576
    unsigned short* WrT  = (unsigned short*)(ws + 27407360); // 1M shorts
    unsigned short* WiT  = (unsigned short*)(ws + 27931648);
    unsigned short* WinT = (unsigned short*)(ws + 28455936);
    unsigned short* Zbf  = (unsigned short*)(ws + 28980224); // 8.4M shorts
    unsigned short* Rbf  = (unsigned short*)(ws + 33174528); // 16.7M shorts

    k_tables<<<512, 256, 0, stream>>>(tabBf);
    k_cvtw<<<614, 256, 0, stream>>>(ff_w0, ff_w1, fa_w, fb_w, fa_b, fb_b,
                                    W0T, W1T, Wcat, bcat);
    k_att<<<1, 128, 0, stream>>>(params, fnu_w1, fnu_b1, fnu_w2, fnu_b2, fnu_w3, fnu_b3, att);
    k_embed<<<16384, 256, 0, stream>>>(xin, in_w, in_b, H, Hbf);

    for (int lay = 0; lay < 4; ++lay) {
        const float* attL = att + lay * 16;
        // -------- Y branch (periodic rfft) --------
        k_wgen<<<dim3(64, 4), 256, 0, stream>>>(fw_y + (long)lay * 2097152, attL, WRb, WIb);
        k_wtr<<<256, 256, 0, stream>>>(WRb, WIb, WrT, WiT, WinT);
        k_tf<<<1024, 256, 0, stream>>>(tabYF, Hbf, 16384L, 64, Zbf);
        k_mixm<<<dim3(4, 256), 256, 0, stream>>>(Zbf, WrT, WiT, WinT);
        k_ti<<<1024, 256, 0, stream>>>(tabYI, Zbf, Rbf, 16384L, 64, 0);
        // -------- X branch (Dirichlet DST) --------
        k_wgen<<<dim3(64, 4), 256, 0, stream>>>(fw_x + (long)lay * 2097152, attL, WRb, WIb);
        k_wtr<<<256, 256, 0, stream>>>(WRb, WIb, WrT, WiT, WinT);
        k_tf<<<1024, 256, 0, stream>>>(tabXF, Hbf, 64L, 16384, Zbf);
        k_mixm<<<dim3(4, 256), 256, 0, stream>>>(Zbf, WrT, WiT, WinT);
        k_ti<<<1024, 256, 0, stream>>>(tabXI, Zbf, Rbf, 64L, 16384, 1);
        // -------- fused FeedForward + LN (+residual / final gelu) --------
        k_ffm<<<4096, 256, 0, stream>>>(
            Rbf, W0T + lay * 16384, ff_b0 + lay * 256,
            W1T + lay * 16384, ff_b1 + lay * 64,
            ln_g + lay * 64, ln_b + lay * 64,
            H, Hbf, (lay == 3) ? 1 : 0);
    }
    k_headm<<<1024, 256, 0, stream>>>(Hbf, xin, Wcat, bcat,
                                      c1_w, c1_b, c2_w, c2_b, out);
}

// Round 6
// 1692.115 us; speedup vs baseline: 3.8022x; 1.2373x over previous
//
#include <hip/hip_runtime.h>
#include <math.h>

// ---------------------------------------------------------------------------
// OmniFluids2D forward on MI355X. bf16 dataflow + MFMA everywhere GEMM-shaped.
// Y/X spectral branches merged into double-width launches. B=4, 256^2, W=64.
// ---------------------------------------------------------------------------

typedef __attribute__((ext_vector_type(8))) short sh8;
typedef __attribute__((ext_vector_type(4))) float f4;
typedef __bf16 bf16x2 __attribute__((ext_vector_type(2)));

#if defined(__has_builtin)
#if __has_builtin(__builtin_amdgcn_fdot2_f32_bf16)
#define HAS_DOT2 1
#endif
#endif

__device__ __forceinline__ float gelu_f(float v) {          // exact (att only)
    return 0.5f * v * (1.0f + erff(v * 0.70710678118654752f));
}
__device__ __forceinline__ float gelu_fast(float v) {       // tanh-approx
    float s = v * (1.5957691216f + 0.0713548162f * v * v);
    return v / (1.0f + __expf(-s));
}
__device__ __forceinline__ unsigned short f2bf(float x) {
    unsigned int u = __float_as_uint(x);
    u += 0x7fffu + ((u >> 16) & 1u);
    return (unsigned short)(u >> 16);
}
__device__ __forceinline__ float bf2f(unsigned short h) {
    return __uint_as_float(((unsigned int)h) << 16);
}
__device__ __forceinline__ float dot2bf(unsigned int a, unsigned int b, float c) {
#ifdef HAS_DOT2
    return __builtin_amdgcn_fdot2_f32_bf16(
        __builtin_bit_cast(bf16x2, a), __builtin_bit_cast(bf16x2, b), c, false);
#else
    return c + bf2f((unsigned short)(a & 0xffff)) * bf2f((unsigned short)(b & 0xffff))
             + bf2f((unsigned short)(a >> 16))    * bf2f((unsigned short)(b >> 16));
#endif
}

// ------------------------- prep: trig tables + weight packing ----------------
__global__ void k_prep(const float* __restrict__ ff_w0, const float* __restrict__ ff_w1,
                       const float* __restrict__ fa_w, const float* __restrict__ fb_w,
                       const float* __restrict__ fa_b, const float* __restrict__ fb_b,
                       const float* __restrict__ c1w, const float* __restrict__ c2w,
                       unsigned short* __restrict__ tabBf,
                       unsigned short* __restrict__ W0T, unsigned short* __restrict__ W1T,
                       unsigned short* __restrict__ Wcat, float* __restrict__ bcat,
                       unsigned int* __restrict__ c1p, unsigned int* __restrict__ c2p) {
    int idx = blockIdx.x * 256 + threadIdx.x;
    if (idx < 131072) {
        int t = idx >> 15, r = idx & 32767;
        const double PI = 3.14159265358979323846;
        const double s510 = 1.0 / sqrt(510.0);
        double v = 0.0;
        if (t == 0) {            // TAB_YF [row=2m+c][y]  (128x256)
            int row = r >> 8, y = r & 255;
            int m = row >> 1, c = row & 1;
            double ang = 2.0 * PI * (double)(m * y) / 256.0;
            v = (c == 0 ? cos(ang) : -sin(ang)) / 16.0;
        } else if (t == 1) {     // TAB_XF [row=2k+c][x]  (128x256)
            int row = r >> 8, xx = r & 255;
            int k = row >> 1, c = row & 1;
            if (c == 0) {
                v = 0.0;
                if (xx == 0)   v = s510;
                if (xx == 255) v = (k & 1) ? -s510 : s510;
            } else {
                double ang = PI * (double)(k * xx) / 255.0;
                v = -2.0 * s510 * sin(ang);
            }
        } else if (t == 2) {     // TAB_YI [y][row=2m+c]  (256x128)
            int y = r >> 7, row = r & 127;
            int m = row >> 1, c = row & 1;
            double ang = 2.0 * PI * (double)(m * y) / 256.0;
            if (c == 0) v = (m == 0 ? 1.0 : 2.0 * cos(ang)) / 16.0;
            else        v = (m == 0 ? 0.0 : -2.0 * sin(ang) / 16.0);
        } else {                 // TAB_XI [x][row=2k+c]  (256x128)
            int xx = r >> 7, row = r & 127;
            int k = row >> 1, c = row & 1;
            double ang = PI * (double)(k * xx) / 255.0;
            if (c == 0) v = s510 * (k == 0 ? 1.0 : 2.0 * cos(ang));
            else        v = (k == 0 ? 0.0 : -2.0 * s510 * sin(ang));
        }
        tabBf[idx] = f2bf((float)v);
        return;
    }
    idx -= 131072;
    if (idx < 65536) {
        int l = idx >> 14, rem = idx & 16383;
        int n = rem >> 6, k = rem & 63;
        W0T[idx] = f2bf(ff_w0[l * 16384 + k * 256 + n]);
    } else if (idx < 131072) {
        int j = idx - 65536;
        int l = j >> 14, rem = j & 16383;
        int n = rem >> 8, k = rem & 255;
        W1T[j] = f2bf(ff_w1[l * 16384 + k * 64 + n]);
    } else if (idx < 156672) {
        int j = idx - 131072;
        int f = j / 5120, r2 = j % 5120;
        int n = r2 >> 6, k = r2 & 63;
        float v = 0.0f;
        if (n < 36)      v = fa_w[f * 2304 + k * 36 + n];
        else if (n < 70) v = fb_w[f * 2176 + k * 34 + (n - 36)];
        Wcat[j] = f2bf(v);
    } else if (idx < 157072) {
        int j = idx - 156672;
        int f = j / 80, n = j % 80;
        float v = 0.0f;
        if (n < 36)      v = fa_b[f * 36 + n];
        else if (n < 70) v = fb_b[f * 34 + (n - 36)];
        bcat[j] = v;
    } else if (idx < 157552) {
        int j = idx - 157072;         // 0..479
        int half = j >= 240;
        int r = j - half * 240;       // r = fc*6 + jj, fc = f*8+c
        int fc = r / 6, jj = r % 6;
        const float* src = half ? c2w : c1w;
        unsigned int u = (unsigned int)f2bf(src[fc * 12 + 2 * jj])
                       | ((unsigned int)f2bf(src[fc * 12 + 2 * jj + 1]) << 16);
        (half ? c2p : c1p)[r] = u;
    }
}

// ------------------------- routing attention (one block per layer) -----------
__global__ void k_att(const float* __restrict__ params,
                      const float* __restrict__ w1, const float* __restrict__ b1,
                      const float* __restrict__ w2, const float* __restrict__ b2,
                      const float* __restrict__ w3, const float* __restrict__ b3,
                      float* __restrict__ att) {
    __shared__ float A1[128], A2[128], LG[4];
    int j = threadIdx.x;   // 128 threads
    int lay = blockIdx.x;
    for (int b = 0; b < 4; ++b) {
        float s = b1[lay * 128 + j];
        for (int p = 0; p < 8; ++p) s += params[b * 8 + p] * w1[(lay * 8 + p) * 128 + j];
        A1[j] = gelu_f(s);
        __syncthreads();
        s = b2[lay * 128 + j];
        for (int q = 0; q < 128; ++q) s += A1[q] * w2[(lay * 128 + q) * 128 + j];
        A2[j] = gelu_f(s);
        __syncthreads();
        if (j < 4) {
            float tacc = b3[lay * 4 + j];
            for (int q = 0; q < 128; ++q) tacc += A2[q] * w3[(lay * 128 + q) * 4 + j];
            LG[j] = tacc * 0.1f;
        }
        __syncthreads();
        if (j == 0) {
            float mx = fmaxf(fmaxf(LG[0], LG[1]), fmaxf(LG[2], LG[3]));
            float e0 = expf(LG[0] - mx), e1 = expf(LG[1] - mx);
            float e2 = expf(LG[2] - mx), e3 = expf(LG[3] - mx);
            float inv = 1.0f / (e0 + e1 + e2 + e3);
            att[lay * 16 + b * 4 + 0] = e0 * inv;
            att[lay * 16 + b * 4 + 1] = e1 * inv;
            att[lay * 16 + b * 4 + 2] = e2 * inv;
            att[lay * 16 + b * 4 + 3] = e3 * inv;
        }
        __syncthreads();
    }
}

// ------------------------- input embedding (bf16 H only) ---------------------
__global__ __launch_bounds__(256) void k_embed(const float* __restrict__ xin,
                        const float* __restrict__ inw, const float* __restrict__ inb,
                        unsigned short* __restrict__ Hb) {
    long gid = (long)blockIdx.x * 256 + threadIdx.x;   // 0..4194303
    long px = gid >> 4;
    int c4 = (int)(gid & 15) * 4;
    int y = (int)(px & 255), xi = (int)((px >> 8) & 255);
    const float* xp = xin + px * 5;
    float v[7];
    v[0] = xp[0]; v[1] = xp[1]; v[2] = xp[2]; v[3] = xp[3]; v[4] = xp[4];
    const float STEP = 6.283185307179586f / 256.0f;
    v[5] = xi * STEP;
    v[6] = y * STEP;
    float r[4];
    #pragma unroll
    for (int c = 0; c < 4; ++c) {
        int ch = c4 + c;
        float s = inb[ch];
        #pragma unroll
        for (int p = 0; p < 7; ++p) s += v[p] * inw[p * 64 + ch];
        r[c] = gelu_fast(s);
    }
    uint2 uu;
    uu.x = (unsigned int)f2bf(r[0]) | ((unsigned int)f2bf(r[1]) << 16);
    uu.y = (unsigned int)f2bf(r[2]) | ((unsigned int)f2bf(r[3]) << 16);
    *(uint2*)(Hb + px * 64 + c4) = uu;
}

// ------------------------- W generation, both branches -----------------------
__global__ __launch_bounds__(256) void k_wgen2(
    const float* __restrict__ fwY, const float* __restrict__ fwX,
    const float* __restrict__ att,
    float* __restrict__ WRy, float* __restrict__ WIy,
    float* __restrict__ WRx, float* __restrict__ WIx) {
    int ii = blockIdx.x, b = blockIdx.y, z = blockIdx.z;
    const float* fw = z ? fwX : fwY;
    float* WRo = z ? WRx : WRy;
    float* WIo = z ? WIx : WIy;
    int tid = threadIdx.x;
    float av[4];
    av[0] = att[b * 4 + 0]; av[1] = att[b * 4 + 1];
    av[2] = att[b * 4 + 2]; av[3] = att[b * 4 + 3];
    float acc[32];
    #pragma unroll
    for (int j = 0; j < 32; ++j) acc[j] = 0.0f;
    const float* base = fw + (long)ii * 8192;
    for (int k = 0; k < 4; ++k) {
        const float* p = base + (long)k * 524288;
        float a = av[k];
        #pragma unroll
        for (int j = 0; j < 32; ++j) acc[j] += a * p[tid + j * 256];
    }
    __shared__ float ldsR[64 * 65], ldsI[64 * 65];
    #pragma unroll
    for (int j = 0; j < 32; ++j) {
        int l = tid + j * 256;                 // l over [o][m][c]
        int o = l >> 7, m = (l >> 1) & 63, c = l & 1;
        (c ? ldsI : ldsR)[o * 65 + m] = acc[j];
    }
    __syncthreads();
    long ob = (long)b * 262144 + (long)ii * 64;
    for (int w = tid; w < 4096; w += 256) {
        int m = w >> 6, o = w & 63;
        WRo[ob + (long)m * 4096 + o] = ldsR[o * 65 + m];
        WIo[ob + (long)m * 4096 + o] = ldsI[o * 65 + m];
    }
}

// ------------------------- W transpose to bf16, both branches ----------------
__global__ __launch_bounds__(256) void k_wtr2(
    const float* __restrict__ WRy, const float* __restrict__ WIy,
    const float* __restrict__ WRx, const float* __restrict__ WIx,
    unsigned short* __restrict__ WrTy, unsigned short* __restrict__ WiTy,
    unsigned short* __restrict__ WinTy,
    unsigned short* __restrict__ WrTx, unsigned short* __restrict__ WiTx,
    unsigned short* __restrict__ WinTx) {
    int z = blockIdx.y;
    const float* WR = z ? WRx : WRy;
    const float* WI = z ? WIx : WIy;
    unsigned short* WrT  = z ? WrTx  : WrTy;
    unsigned short* WiT  = z ? WiTx  : WiTy;
    unsigned short* WinT = z ? WinTx : WinTy;
    __shared__ float lR[64 * 65], lI[64 * 65];
    long base = (long)blockIdx.x * 4096;    // (b*64+m)
    int tid = threadIdx.x;
    #pragma unroll
    for (int it = 0; it < 16; ++it) {
        int l = it * 256 + tid;
        int i = l >> 6, o = l & 63;
        lR[i * 65 + o] = WR[base + l];
        lI[i * 65 + o] = WI[base + l];
    }
    __syncthreads();
    #pragma unroll
    for (int it = 0; it < 16; ++it) {
        int l = it * 256 + tid;
        int o = l >> 6, i = l & 63;
        float rr = lR[i * 65 + o], im = lI[i * 65 + o];
        WrT[base + l]  = f2bf(rr);
        WiT[base + l]  = f2bf(im);
        WinT[base + l] = f2bf(-im);
    }
}

// ------------------------- B^T staging: global rows -> lds[n][k] -------------
__device__ __forceinline__ void stage_bt(unsigned short* lds, int pitch,
    const unsigned short* src, int rowStride, int K, int tid)
{
    int pairs = K >> 1;
    int tasks = pairs * 8;
    for (int idx = tid; idx < tasks; idx += 256) {
        int p = idx & (pairs - 1);
        int cg = idx / pairs;
        const unsigned short* s0 = src + (long)(2 * p) * rowStride + cg * 8;
        sh8 r0 = *(const sh8*)s0;
        sh8 r1 = *(const sh8*)(s0 + rowStride);
        unsigned short* dbase = lds + cg * 8 * pitch + 2 * p;
        #pragma unroll
        for (int j = 0; j < 8; ++j) {
            unsigned int u = (unsigned int)(unsigned short)r0[j]
                           | ((unsigned int)(unsigned short)r1[j] << 16);
            *(unsigned int*)(dbase + j * pitch) = u;
        }
    }
}

// ------------------------- MFMA forward transform, both branches -------------
__global__ __launch_bounds__(256) void k_tf2(
    const unsigned short* __restrict__ tabY, const unsigned short* __restrict__ tabX,
    const unsigned short* __restrict__ Hb,
    unsigned short* __restrict__ Zy, unsigned short* __restrict__ Zx)
{
    __shared__ __align__(16) unsigned short ldsB[64 * 272];
    int g = blockIdx.x, br = blockIdx.y;
    int b = g >> 8, s = g & 255;
    const unsigned short* tab = br ? tabX : tabY;
    unsigned short* Zo = br ? Zx : Zy;
    long sLo = br ? 64L : 16384L;
    int rowStride = br ? 16384 : 64;
    int tid = threadIdx.x;
    const unsigned short* src = Hb + (long)b * 4194304 + (long)s * sLo;
    stage_bt(ldsB, 272, src, rowStride, 256, tid);
    __syncthreads();
    int w = tid >> 6, lane = tid & 63, q = lane >> 4, ln = lane & 15;
    f4 acc[2][4];
    #pragma unroll
    for (int mi = 0; mi < 2; ++mi)
        #pragma unroll
        for (int ni = 0; ni < 4; ++ni) acc[mi][ni] = (f4){0.f, 0.f, 0.f, 0.f};
    for (int kc = 0; kc < 256; kc += 32) {
        sh8 a[2], bf[4];
        #pragma unroll
        for (int mi = 0; mi < 2; ++mi)
            a[mi] = *(const sh8*)(tab + (w * 32 + mi * 16 + ln) * 256 + kc + q * 8);
        #pragma unroll
        for (int ni = 0; ni < 4; ++ni)
            bf[ni] = *(const sh8*)(ldsB + (ni * 16 + ln) * 272 + kc + q * 8);
        #pragma unroll
        for (int mi = 0; mi < 2; ++mi)
            #pragma unroll
            for (int ni = 0; ni < 4; ++ni)
                acc[mi][ni] = __builtin_amdgcn_mfma_f32_16x16x32_bf16(
                    a[mi], bf[ni], acc[mi][ni], 0, 0, 0);
    }
    long zB = (long)b * 2097152 + (long)s * 8192;
    #pragma unroll
    for (int mi = 0; mi < 2; ++mi)
        #pragma unroll
        for (int ni = 0; ni < 4; ++ni)
            #pragma unroll
            for (int reg = 0; reg < 4; ++reg) {
                int r = w * 32 + mi * 16 + q * 4 + reg;
                Zo[zB + r * 64 + ni * 16 + ln] = f2bf(acc[mi][ni][reg]);
            }
}

// ------------------------- MFMA complex mode-mix, both branches --------------
__global__ __launch_bounds__(256) void k_mixm2(
    unsigned short* Zy, unsigned short* Zx,
    const unsigned short* __restrict__ WrTy, const unsigned short* __restrict__ WiTy,
    const unsigned short* __restrict__ WinTy,
    const unsigned short* __restrict__ WrTx, const unsigned short* __restrict__ WiTx,
    const unsigned short* __restrict__ WinTx)
{
    int xt = blockIdx.x, g = blockIdx.y, z = blockIdx.z;
    unsigned short* Z = z ? Zx : Zy;
    const unsigned short* WrT  = z ? WrTx  : WrTy;
    const unsigned short* WiT  = z ? WiTx  : WiTy;
    const unsigned short* WinT = z ? WinTx : WinTy;
    int b = g >> 6, m = g & 63;
    int tid = threadIdx.x, w = tid >> 6, lane = tid & 63, q = lane >> 4, ln = lane & 15;
    long zB = (long)b * 2097152 + (long)m * 128;
    long wB = (long)b * 262144 + (long)m * 4096;
    int s0 = xt * 64 + w * 16;
    f4 aR[4], aI[4];
    #pragma unroll
    for (int nt = 0; nt < 4; ++nt) { aR[nt] = (f4){0.f,0.f,0.f,0.f}; aI[nt] = (f4){0.f,0.f,0.f,0.f}; }
    for (int kc = 0; kc < 64; kc += 32) {
        sh8 zr = *(const sh8*)(Z + zB + (long)(s0 + ln) * 8192 + kc + q * 8);
        sh8 zi = *(const sh8*)(Z + zB + (long)(s0 + ln) * 8192 + 64 + kc + q * 8);
        #pragma unroll
        for (int nt = 0; nt < 4; ++nt) {
            int o = nt * 16 + ln;
            sh8 wr = *(const sh8*)(WrT + wB + o * 64 + kc + q * 8);
            sh8 wi = *(const sh8*)(WiT + wB + o * 64 + kc + q * 8);
            sh8 wn = *(const sh8*)(WinT + wB + o * 64 + kc + q * 8);
            aR[nt] = __builtin_amdgcn_mfma_f32_16x16x32_bf16(zr, wr, aR[nt], 0, 0, 0);
            aR[nt] = __builtin_amdgcn_mfma_f32_16x16x32_bf16(zi, wn, aR[nt], 0, 0, 0);
            aI[nt] = __builtin_amdgcn_mfma_f32_16x16x32_bf16(zr, wi, aI[nt], 0, 0, 0);
            aI[nt] = __builtin_amdgcn_mfma_f32_16x16x32_bf16(zi, wr, aI[nt], 0, 0, 0);
        }
    }
    #pragma unroll
    for (int nt = 0; nt < 4; ++nt)
        #pragma unroll
        for (int reg = 0; reg < 4; ++reg) {
            int s = s0 + q * 4 + reg;
            long a = zB + (long)s * 8192 + nt * 16 + ln;
            Z[a]      = f2bf(aR[nt][reg]);
            Z[a + 64] = f2bf(aI[nt][reg]);
        }
}

// ------------------------- MFMA inverse transform, both branches -------------
// z=0: Ry[b][x][y][o] from Zy ; z=1: Rx[b][y][x][o] from Zx (both contiguous).
__global__ __launch_bounds__(256) void k_ti2(
    const unsigned short* __restrict__ tabY, const unsigned short* __restrict__ tabX,
    const unsigned short* __restrict__ Zy, const unsigned short* __restrict__ Zx,
    unsigned short* __restrict__ Ry, unsigned short* __restrict__ Rx)
{
    __shared__ __align__(16) unsigned short ldsB[64 * 144];
    int g = blockIdx.x, br = blockIdx.y;
    int b = g >> 8, s = g & 255;
    const unsigned short* tab = br ? tabX : tabY;
    const unsigned short* Zl  = br ? Zx : Zy;
    unsigned short* Ro = br ? Rx : Ry;
    int tid = threadIdx.x;
    const unsigned short* src = Zl + (long)b * 2097152 + (long)s * 8192;
    stage_bt(ldsB, 144, src, 64, 128, tid);
    __syncthreads();
    int w = tid >> 6, lane = tid & 63, q = lane >> 4, ln = lane & 15;
    f4 acc[4][4];
    #pragma unroll
    for (int mi = 0; mi < 4; ++mi)
        #pragma unroll
        for (int ni = 0; ni < 4; ++ni) acc[mi][ni] = (f4){0.f, 0.f, 0.f, 0.f};
    for (int kc = 0; kc < 128; kc += 32) {
        sh8 a[4], bf[4];
        #pragma unroll
        for (int mi = 0; mi < 4; ++mi)
            a[mi] = *(const sh8*)(tab + (w * 64 + mi * 16 + ln) * 128 + kc + q * 8);
        #pragma unroll
        for (int ni = 0; ni < 4; ++ni)
            bf[ni] = *(const sh8*)(ldsB + (ni * 16 + ln) * 144 + kc + q * 8);
        #pragma unroll
        for (int mi = 0; mi < 4; ++mi)
            #pragma unroll
            for (int ni = 0; ni < 4; ++ni)
                acc[mi][ni] = __builtin_amdgcn_mfma_f32_16x16x32_bf16(
                    a[mi], bf[ni], acc[mi][ni], 0, 0, 0);
    }
    long rB = (long)b * 4194304 + (long)s * 16384;
    #pragma unroll
    for (int mi = 0; mi < 4; ++mi)
        #pragma unroll
        for (int ni = 0; ni < 4; ++ni)
            #pragma unroll
            for (int reg = 0; reg < 4; ++reg) {
                int r2 = w * 64 + mi * 16 + q * 4 + reg;
                Ro[rB + (long)r2 * 64 + ni * 16 + ln] = f2bf(acc[mi][ni][reg]);
            }
}

// ------------------------- MFMA fused FeedForward + LN -----------------------
// A = bf16(Ry + Rx) built in registers; residual stream in bf16 (Hb).
__global__ __launch_bounds__(256) void k_ffm(
    const unsigned short* __restrict__ Ry, const unsigned short* __restrict__ Rx,
    const unsigned short* __restrict__ W0T, const float* __restrict__ b0,
    const unsigned short* __restrict__ W1T, const float* __restrict__ b1,
    const float* __restrict__ g1, const float* __restrict__ be1,
    unsigned short* __restrict__ Hb, int last)
{
    __shared__ __align__(16) unsigned short T[64 * 264];
    int m0 = blockIdx.x * 64;
    int tid = threadIdx.x, w = tid >> 6, lane = tid & 63, q = lane >> 4, ln = lane & 15;
    int row = m0 + w * 16 + ln;
    int bb = row >> 16, xx2 = (row >> 8) & 255, yy = row & 255;
    const unsigned short* ryp = Ry + (long)row * 64;
    const unsigned short* rxp = Rx + (long)bb * 4194304 + (long)yy * 16384 + xx2 * 64;
    // phase 1: T = relu((Ry+Rx) @ W0 + b0), rows w*16..+15, N=256
    {
        f4 acc1[16];
        #pragma unroll
        for (int nt = 0; nt < 16; ++nt) acc1[nt] = (f4){0.f, 0.f, 0.f, 0.f};
        for (int kc = 0; kc < 64; kc += 32) {
            sh8 ry = *(const sh8*)(ryp + kc + q * 8);
            sh8 rx = *(const sh8*)(rxp + kc + q * 8);
            sh8 a;
            #pragma unroll
            for (int j = 0; j < 8; ++j)
                a[j] = (short)f2bf(bf2f((unsigned short)ry[j]) + bf2f((unsigned short)rx[j]));
            #pragma unroll
            for (int nt = 0; nt < 16; ++nt) {
                sh8 bf = *(const sh8*)(W0T + (nt * 16 + ln) * 64 + kc + q * 8);
                acc1[nt] = __builtin_amdgcn_mfma_f32_16x16x32_bf16(a, bf, acc1[nt], 0, 0, 0);
            }
        }
        #pragma unroll
        for (int nt = 0; nt < 16; ++nt) {
            int n = nt * 16 + ln;
            float bias = b0[n];
            #pragma unroll
            for (int reg = 0; reg < 4; ++reg) {
                int m = w * 16 + q * 4 + reg;
                T[m * 264 + n] = f2bf(fmaxf(acc1[nt][reg] + bias, 0.0f));
            }
        }
    }
    // phase 2 (intra-wave LDS dep): t = T @ W1 + b1, then LN + residual
    f4 acc2[4];
    #pragma unroll
    for (int nt = 0; nt < 4; ++nt) acc2[nt] = (f4){0.f, 0.f, 0.f, 0.f};
    for (int kc = 0; kc < 256; kc += 32) {
        sh8 a = *(const sh8*)(T + (w * 16 + ln) * 264 + kc + q * 8);
        #pragma unroll
        for (int nt = 0; nt < 4; ++nt) {
            sh8 bf = *(const sh8*)(W1T + (nt * 16 + ln) * 256 + kc + q * 8);
            acc2[nt] = __builtin_amdgcn_mfma_f32_16x16x32_bf16(a, bf, acc2[nt], 0, 0, 0);
        }
    }
    float bia[4], gg[4], bb4[4];
    #pragma unroll
    for (int nt = 0; nt < 4; ++nt) {
        int n = nt * 16 + ln;
        bia[nt] = b1[n]; gg[nt] = g1[n]; bb4[nt] = be1[n];
    }
    #pragma unroll
    for (int reg = 0; reg < 4; ++reg) {
        float t[4];
        float s = 0.f, qs = 0.f;
        #pragma unroll
        for (int nt = 0; nt < 4; ++nt) {
            t[nt] = acc2[nt][reg] + bia[nt];
            s += t[nt]; qs += t[nt] * t[nt];
        }
        #pragma unroll
        for (int d = 1; d < 16; d <<= 1) {
            s  += __shfl_xor(s, d, 64);
            qs += __shfl_xor(qs, d, 64);
        }
        float mean = s * (1.0f / 64.0f);
        float var  = qs * (1.0f / 64.0f) - mean * mean;
        float inv  = rsqrtf(var + 1e-5f);
        int m = w * 16 + q * 4 + reg;
        long base = (long)(m0 + m) * 64;
        #pragma unroll
        for (int nt = 0; nt < 4; ++nt) {
            int n = nt * 16 + ln;
            float v = (t[nt] - mean) * inv * gg[nt] + bb4[nt];
            float hv;
            if (last) hv = gelu_fast(v);
            else      hv = bf2f(Hb[base + n]) + v;
            Hb[base + n] = f2bf(hv);
        }
    }
}

// ------------------------- output heads (MFMA ha + dot2 conv) ----------------
__global__ __launch_bounds__(256) void k_headm(
    const unsigned short* __restrict__ Hb, const float* __restrict__ x0,
    const unsigned short* __restrict__ Wcat, const float* __restrict__ bcat,
    const unsigned int* __restrict__ c1p, const float* __restrict__ c1b,
    const unsigned int* __restrict__ c2p, const float* __restrict__ c2b,
    float* __restrict__ out)
{
    __shared__ unsigned short ha[256 * 74];   // [px][j], pitch 74 (gcd(37,32)=1)
    int tid = threadIdx.x;
    long px0 = (long)blockIdx.x * 256;
    int w = tid >> 6, lane = tid & 63, q = lane >> 4, ln = lane & 15;
    // A-fragments of the ha-GEMM: load once, reuse across all 5 f
    sh8 aF[4][2];
    #pragma unroll
    for (int mi = 0; mi < 4; ++mi)
        #pragma unroll
        for (int kc = 0; kc < 2; ++kc)
            aF[mi][kc] = *(const sh8*)(Hb + (px0 + w * 64 + mi * 16 + ln) * 64
                                        + kc * 32 + q * 8);
    for (int f = 0; f < 5; ++f) {
        f4 acc[4][5];
        #pragma unroll
        for (int mi = 0; mi < 4; ++mi)
            #pragma unroll
            for (int nt = 0; nt < 5; ++nt) acc[mi][nt] = (f4){0.f, 0.f, 0.f, 0.f};
        #pragma unroll
        for (int kc = 0; kc < 2; ++kc) {
            sh8 bf[5];
            #pragma unroll
            for (int nt = 0; nt < 5; ++nt)
                bf[nt] = *(const sh8*)(Wcat + f * 5120 + (nt * 16 + ln) * 64
                                        + kc * 32 + q * 8);
            #pragma unroll
            for (int mi = 0; mi < 4; ++mi)
                #pragma unroll
                for (int nt = 0; nt < 5; ++nt)
                    acc[mi][nt] = __builtin_amdgcn_mfma_f32_16x16x32_bf16(
                        aF[mi][kc], bf[nt], acc[mi][nt], 0, 0, 0);
        }
        __syncthreads();   // previous iteration's conv reads done
        #pragma unroll
        for (int nt = 0; nt < 5; ++nt) {
            int n = nt * 16 + ln;
            if (n < 70) {
                float bias = bcat[f * 80 + n];
                #pragma unroll
                for (int mi = 0; mi < 4; ++mi)
                    #pragma unroll
                    for (int reg = 0; reg < 4; ++reg) {
                        int m = w * 64 + mi * 16 + q * 4 + reg;
                        ha[m * 74 + n] = f2bf(gelu_fast(acc[mi][nt][reg] + bias));
                    }
            }
        }
        __syncthreads();
        // conv phase: one pixel per thread, bf16-pair dot products
        unsigned int hp[35];
        #pragma unroll
        for (int i = 0; i < 35; ++i)
            hp[i] = *(const unsigned int*)(ha + tid * 74 + 2 * i);
        float b2v = c2b[f];
        float u2[10];
        #pragma unroll
        for (int d = 0; d < 10; ++d) u2[d] = b2v;
        for (int c = 0; c < 8; ++c) {
            int fc = f * 8 + c;
            unsigned int w1p[6], w2p[6];
            #pragma unroll
            for (int j = 0; j < 6; ++j) { w1p[j] = c1p[fc * 6 + j]; w2p[j] = c2p[fc * 6 + j]; }
            float bc = c1b[fc];
            unsigned int u1p[15];
            #pragma unroll
            for (int p2 = 0; p2 < 15; ++p2) {
                float sa = bc, sb = bc;
                #pragma unroll
                for (int j = 0; j < 6; ++j) {
                    sa = dot2bf(hp[2 * p2 + j], w1p[j], sa);
                    sb = dot2bf(hp[2 * p2 + 1 + j], w1p[j], sb);
                }
                u1p[p2] = (unsigned int)f2bf(gelu_fast(sa))
                        | ((unsigned int)f2bf(gelu_fast(sb)) << 16);
            }
            #pragma unroll
            for (int p2 = 0; p2 < 10; ++p2) {
                float s = u2[p2];
                #pragma unroll
                for (int j = 0; j < 6; ++j) s = dot2bf(u1p[p2 + j], w2p[j], s);
                u2[p2] = s;
            }
        }
        long px = px0 + tid;
        float xv = x0[px * 5 + f];
        #pragma unroll
        for (int d = 0; d < 10; ++d)
            out[px * 50 + f * 10 + d] = xv + u2[d] * (float)(d + 1) * 0.1f;
    }
}

// ---------------------------------------------------------------------------
extern "C" void kernel_launch(void* const* d_in, const int* in_sizes, int n_in,
                              void* d_out, int out_size, void* d_ws, size_t ws_size,
                              hipStream_t stream) {
    (void)in_sizes; (void)n_in; (void)out_size; (void)ws_size;
    const float* xin    = (const float*)d_in[0];
    const float* params = (const float*)d_in[1];
    const float* in_w   = (const float*)d_in[2];
    const float* in_b   = (const float*)d_in[3];
    const float* fnu_w1 = (const float*)d_in[4];
    const float* fnu_b1 = (const float*)d_in[5];
    const float* fnu_w2 = (const float*)d_in[6];
    const float* fnu_b2 = (const float*)d_in[7];
    const float* fnu_w3 = (const float*)d_in[8];
    const float* fnu_b3 = (const float*)d_in[9];
    const float* fw_y   = (const float*)d_in[10];
    const float* fw_x   = (const float*)d_in[11];
    const float* ff_w0  = (const float*)d_in[12];
    const float* ff_b0  = (const float*)d_in[13];
    const float* ff_w1  = (const float*)d_in[14];
    const float* ff_b1  = (const float*)d_in[15];
    const float* ln_g   = (const float*)d_in[16];
    const float* ln_b   = (const float*)d_in[17];
    const float* fa_w   = (const float*)d_in[18];
    const float* fa_b   = (const float*)d_in[19];
    const float* fb_w   = (const float*)d_in[20];
    const float* fb_b   = (const float*)d_in[21];
    const float* c1_w   = (const float*)d_in[22];
    const float* c1_b   = (const float*)d_in[23];
    const float* c2_w   = (const float*)d_in[24];
    const float* c2_b   = (const float*)d_in[25];
    float* out = (float*)d_out;
    float* ws  = (float*)d_ws;

    // workspace (float offsets), total ~41.0M floats (~164 MB)
    unsigned short* tabBf = (unsigned short*)(ws + 0);        // 131072 sh
    unsigned short* tabYF = tabBf;
    unsigned short* tabXF = tabBf + 32768;
    unsigned short* tabYI = tabBf + 65536;
    unsigned short* tabXI = tabBf + 98304;
    unsigned short* W0T   = (unsigned short*)(ws + 65536);    // 65536 sh
    unsigned short* W1T   = (unsigned short*)(ws + 98304);    // 65536 sh
    unsigned short* Wcat  = (unsigned short*)(ws + 131072);   // 25600 sh
    float* bcat = ws + 143872;                                 // 400
    float* att  = ws + 144272;                                 // 64
    unsigned int* c1p = (unsigned int*)(ws + 144336);          // 240
    unsigned int* c2p = (unsigned int*)(ws + 144576);          // 240
    unsigned short* Hbf = (unsigned short*)(ws + 144816);      // 16.8M sh
    float* WRy = ws + 8533424;   // 1048576 each
    float* WIy = ws + 9582000;
    float* WRx = ws + 10630576;
    float* WIx = ws + 11679152;
    unsigned short* WrTy  = (unsigned short*)(ws + 12727728);  // 1M sh each
    unsigned short* WiTy  = (unsigned short*)(ws + 13252016);
    unsigned short* WinTy = (unsigned short*)(ws + 13776304);
    unsigned short* WrTx  = (unsigned short*)(ws + 14300592);
    unsigned short* WiTx  = (unsigned short*)(ws + 14824880);
    unsigned short* WinTx = (unsigned short*)(ws + 15349168);
    unsigned short* Zy    = (unsigned short*)(ws + 15873456);  // 8.4M sh
    unsigned short* Zx    = (unsigned short*)(ws + 20067760);  // 8.4M sh
    unsigned short* Ry    = (unsigned short*)(ws + 24262064);  // 16.8M sh
    unsigned short* Rx    = (unsigned short*)(ws + 32650672);  // 16.8M sh

    k_prep<<<1128, 256, 0, stream>>>(ff_w0, ff_w1, fa_w, fb_w, fa_b, fb_b,
                                     c1_w, c2_w, tabBf, W0T, W1T, Wcat, bcat, c1p, c2p);
    k_att<<<4, 128, 0, stream>>>(params, fnu_w1, fnu_b1, fnu_w2, fnu_b2, fnu_w3, fnu_b3, att);
    k_embed<<<16384, 256, 0, stream>>>(xin, in_w, in_b, Hbf);

    for (int lay = 0; lay < 4; ++lay) {
        const float* attL = att + lay * 16;
        k_wgen2<<<dim3(64, 4, 2), 256, 0, stream>>>(
            fw_y + (long)lay * 2097152, fw_x + (long)lay * 2097152, attL,
            WRy, WIy, WRx, WIx);
        k_wtr2<<<dim3(256, 2), 256, 0, stream>>>(
            WRy, WIy, WRx, WIx, WrTy, WiTy, WinTy, WrTx, WiTx, WinTx);
        k_tf2<<<dim3(1024, 2), 256, 0, stream>>>(tabYF, tabXF, Hbf, Zy, Zx);
        k_mixm2<<<dim3(4, 256, 2), 256, 0, stream>>>(
            Zy, Zx, WrTy, WiTy, WinTy, WrTx, WiTx, WinTx);
        k_ti2<<<dim3(1024, 2), 256, 0, stream>>>(tabYI, tabXI, Zy, Zx, Ry, Rx);
        k_ffm<<<4096, 256, 0, stream>>>(
            Ry, Rx, W0T + lay * 16384, ff_b0 + lay * 256,
            W1T + lay * 16384, ff_b1 + lay * 64,
            ln_g + lay * 64, ln_b + lay * 64,
            Hbf, (lay == 3) ? 1 : 0);
    }
    k_headm<<<1024, 256, 0, stream>>>(Hbf, xin, Wcat, bcat,
                                      c1p, c1_b, c2p, c2_b, out);
}